// Round 3
// baseline (4115.007 us; speedup 1.0000x reference)
//
#include <hip/hip_runtime.h>
#include <math.h>

#define TT 8
#define BB 32
#define VV 50257
#define DD 256
#define NN 4096
#define EPS_ 1e-12f

typedef __attribute__((ext_vector_type(8))) short short8;
typedef __attribute__((ext_vector_type(4))) float f32x4;

__device__ __forceinline__ float sigf(float x) { return 1.f / (1.f + expf(-x)); }
__device__ __forceinline__ float softplusf_(float x) { return fmaxf(x, 0.f) + log1pf(expf(-fabsf(x))); }
__device__ __forceinline__ unsigned short f2bf(float f) {
  union { float f; unsigned u; } c; c.f = f;
  return (unsigned short)((c.u + 0x7FFFu + ((c.u >> 16) & 1u)) >> 16);
}
__device__ __forceinline__ float bf2f(unsigned u16) {
  union { unsigned u; float f; } c; c.u = u16 << 16; return c.f;
}

// ---- block reductions (256-thread blocks only) ----
__device__ __forceinline__ float blk_sum(float v, float* s) {
#pragma unroll
  for (int o = 32; o > 0; o >>= 1) v += __shfl_down(v, o);
  __syncthreads();
  if ((threadIdx.x & 63) == 0) s[threadIdx.x >> 6] = v;
  __syncthreads();
  return s[0] + s[1] + s[2] + s[3];
}
__device__ __forceinline__ float blk_max(float v, float* s) {
#pragma unroll
  for (int o = 32; o > 0; o >>= 1) v = fmaxf(v, __shfl_down(v, o));
  __syncthreads();
  if ((threadIdx.x & 63) == 0) s[threadIdx.x >> 6] = v;
  __syncthreads();
  return fmaxf(fmaxf(s[0], s[1]), fmaxf(s[2], s[3]));
}

// ---- one-time init: one-hot weights + hpe row 0 (zeros + pe[0]) ----
__global__ void init_k(float* rw, float* ww, float* hpe) {
  int i = blockIdx.x * 256 + threadIdx.x;
  if (i < BB) { rw[(size_t)i * NN] = 1.f; ww[(size_t)i * NN] = 1.f; }
  if (i < BB * DD) hpe[i] = (i & 1) ? 1.f : 0.f;
}

// ---- head_W f32 -> bf16 ----
__global__ void cvtw_k(const float* __restrict__ W, unsigned short* __restrict__ Wh, int n4) {
  int i = blockIdx.x * 256 + threadIdx.x;
  if (i >= n4) return;
  float4 v = *(const float4*)(W + (size_t)i * 4);
  unsigned u0 = (unsigned)f2bf(v.x) | ((unsigned)f2bf(v.y) << 16);
  unsigned u1 = (unsigned)f2bf(v.z) | ((unsigned)f2bf(v.w) << 16);
  uint2 p; p.x = u0; p.y = u1;
  *(uint2*)(Wh + (size_t)i * 4) = p;
}

// ---- combined LSTM weights, gate-interleaved rows n' = d*4+gate, K=512 ----
__global__ void catlstm_k(const float* __restrict__ Wih, const float* __restrict__ Whh,
                          const float* __restrict__ bih, const float* __restrict__ bhh,
                          float* __restrict__ Wc, float* __restrict__ cb) {
  int i = blockIdx.x * 256 + threadIdx.x;
  if (i >= 2 * 1024 * 512) return;
  int k = i & 511, np = (i >> 9) & 1023, l = i >> 19;
  int d = np >> 2, gate = np & 3;
  int src = gate * 256 + d;
  Wc[i] = (k < 256) ? Wih[((size_t)l * 1024 + src) * 256 + k]
                    : Whh[((size_t)l * 1024 + src) * 256 + (k - 256)];
  if (k == 0) cb[l * 1024 + np] = bih[l * 1024 + src] + bhh[l * 1024 + src];
}

// ---- combined read/write param weights (1036 x 256) + bias ----
__global__ void catrw_k(const float* __restrict__ rW, const float* __restrict__ rb,
                        const float* __restrict__ wW, const float* __restrict__ wb,
                        float* __restrict__ Wrw, float* __restrict__ brw) {
  int i = blockIdx.x * 256 + threadIdx.x;
  if (i >= 1036 * 256) return;
  int k = i & 255, n = i >> 8;
  Wrw[i] = (n < 262) ? rW[(size_t)n * 256 + k] : wW[(size_t)(n - 262) * 256 + k];
  if (k == 0) brw[n] = (n < 262) ? rb[n] : wb[n - 262];
}

// ================= per-step transformer megakernel: one block per batch ====
__global__ __launch_bounds__(256) void tf_k(
    const int* __restrict__ tokens, const float* __restrict__ embW,
    const float* __restrict__ rgW, const float* __restrict__ rgb,
    const float* __restrict__ filmW, const float* __restrict__ filmb,
    const float* __restrict__ record, const float* __restrict__ rvec,
    const float* __restrict__ Wqkv, const float* __restrict__ bqkv,
    const float* __restrict__ Wo, const float* __restrict__ bo,
    const float* __restrict__ ln1g, const float* __restrict__ ln1b,
    const float* __restrict__ ln2g, const float* __restrict__ ln2b,
    const float* __restrict__ W1, const float* __restrict__ b1,
    const float* __restrict__ W2, const float* __restrict__ b2,
    const float* __restrict__ olng, const float* __restrict__ olnb,
    float* __restrict__ hpe, float* __restrict__ c_out,
    float* __restrict__ lstm_in, int t) {
  __shared__ float h[9][256];
  __shared__ float x[9][256];
  __shared__ float scr[9][1024];
  __shared__ float lgS[4][9][12];
  __shared__ float rec[256];
  __shared__ float s8[8];
  const int b = blockIdx.x, tid = threadIdx.x;
  const int S = t + 2;

  // phase 0: load history rows, compute new x_in row (+PE), append
  for (int s = 0; s < S - 1; ++s) h[s][tid] = hpe[((size_t)s * BB + b) * 256 + tid];
  rec[tid] = record[b * 256 + tid];
  __syncthreads();
  {
    const float* f1 = filmW + (size_t)tid * 256;
    const float* f2 = filmW + (size_t)(256 + tid) * 256;
    const float* g1 = rgW + (size_t)tid * 256;
    float a1 = 0.f, a2 = 0.f, a3 = 0.f;
    for (int k = 0; k < 256; k += 4) {
      float4 rv = *(const float4*)&rec[k];
      float4 w1 = *(const float4*)(f1 + k);
      float4 w2 = *(const float4*)(f2 + k);
      float4 w3 = *(const float4*)(g1 + k);
      a1 += rv.x * w1.x + rv.y * w1.y + rv.z * w1.z + rv.w * w1.w;
      a2 += rv.x * w2.x + rv.y * w2.y + rv.z * w2.z + rv.w * w2.w;
      a3 += rv.x * w3.x + rv.y * w3.y + rv.z * w3.z + rv.w * w3.w;
    }
    float gam = 1.f + tanhf(a1 + filmb[tid]);
    float bet = a2 + filmb[256 + tid];
    float rg = sigf(a3 + rgb[tid]);
    int tok = tokens[t * BB + b];
    float emb = embW[(size_t)tok * 256 + tid];
    float ang = (float)(t + 1) * expf(-logf(10000.f) * (float)(tid & ~1) / 256.f);
    float pe = (tid & 1) ? cosf(ang) : sinf(ang);
    float xv = gam * emb + bet + rg * rvec[b * 256 + tid] + pe;
    h[S - 1][tid] = xv;
    hpe[((size_t)(S - 1) * BB + b) * 256 + tid] = xv;
  }
  __syncthreads();

  for (int l = 0; l < 2; ++l) {
    const int s_lo = (l == 1) ? S - 1 : 0;
    const float* wq = Wqkv + (size_t)l * 768 * 256;
    const float* bq = bqkv + l * 768;
    const float* wo = Wo + (size_t)l * 256 * 256;
    const float* bol = bo + l * 256;
    const float* g1p = ln1g + l * 256; const float* b1p = ln1b + l * 256;
    const float* g2p = ln2g + l * 256; const float* b2p = ln2b + l * 256;
    const float* w1l = W1 + (size_t)l * 1024 * 256; const float* bb1 = b1 + l * 1024;
    const float* w2l = W2 + (size_t)l * 256 * 1024; const float* bb2 = b2 + l * 256;

    // ln1 -> x (all rows), wave-parallel per row
    {
      int w = tid >> 6, lane = tid & 63;
      for (int s = w; s < S; s += 4) {
        float4 v4 = *(const float4*)&h[s][lane << 2];
        float su = v4.x + v4.y + v4.z + v4.w;
        float sq = v4.x * v4.x + v4.y * v4.y + v4.z * v4.z + v4.w * v4.w;
#pragma unroll
        for (int o = 32; o > 0; o >>= 1) { su += __shfl_down(su, o); sq += __shfl_down(sq, o); }
        su = __shfl(su, 0); sq = __shfl(sq, 0);
        float mu = su * (1.f / 256.f);
        float var = fmaxf(sq * (1.f / 256.f) - mu * mu, 0.f);
        float rs = rsqrtf(var + 1e-5f);
        float4 g4 = *(const float4*)(g1p + (lane << 2));
        float4 bt4 = *(const float4*)(b1p + (lane << 2));
        x[s][(lane << 2) + 0] = (v4.x - mu) * rs * g4.x + bt4.x;
        x[s][(lane << 2) + 1] = (v4.y - mu) * rs * g4.y + bt4.y;
        x[s][(lane << 2) + 2] = (v4.z - mu) * rs * g4.z + bt4.z;
        x[s][(lane << 2) + 3] = (v4.w - mu) * rs * g4.w + bt4.w;
      }
    }
    __syncthreads();

    // qkv: thread owns dims tid (q), tid+256 (k), tid+512 (v)
    {
      const float* w0 = wq + (size_t)tid * 256;
      const float* w1 = wq + (size_t)(256 + tid) * 256;
      const float* w2 = wq + (size_t)(512 + tid) * 256;
      float a0[9] = {}, a1[9] = {}, a2[9] = {};
      for (int k = 0; k < 256; k += 4) {
        float4 W0 = *(const float4*)(w0 + k);
        float4 W1v = *(const float4*)(w1 + k);
        float4 W2v = *(const float4*)(w2 + k);
#pragma unroll
        for (int s = 0; s < 9; ++s) {
          if (s < S) {
            float4 xv = *(const float4*)&x[s][k];
            a0[s] += xv.x * W0.x + xv.y * W0.y + xv.z * W0.z + xv.w * W0.w;
            a1[s] += xv.x * W1v.x + xv.y * W1v.y + xv.z * W1v.z + xv.w * W1v.w;
            a2[s] += xv.x * W2v.x + xv.y * W2v.y + xv.z * W2v.z + xv.w * W2v.w;
          }
        }
      }
#pragma unroll
      for (int s = 0; s < 9; ++s) {
        if (s < S) {
          scr[s][tid] = a0[s] + bq[tid];
          scr[s][256 + tid] = a1[s] + bq[256 + tid];
          scr[s][512 + tid] = a2[s] + bq[512 + tid];
        }
      }
    }
    __syncthreads();

    // attention (4 heads x 64 lanes)
    {
      int hh = tid >> 6, lane = tid & 63;
      int npair = (l == 1) ? S : S * S;
      for (int p = lane; p < npair; p += 64) {
        int s = (l == 1) ? S - 1 : p / S;
        int t2 = (l == 1) ? p : p % S;
        const float* qrow = &scr[s][hh * 64];
        const float* krow = &scr[t2][256 + hh * 64];
        float acc = 0.f;
        for (int d = 0; d < 64; d += 4) {
          float4 q4 = *(const float4*)(qrow + d);
          float4 k4 = *(const float4*)(krow + d);
          acc += q4.x * k4.x + q4.y * k4.y + q4.z * k4.z + q4.w * k4.w;
        }
        lgS[hh][s][t2] = acc * 0.125f;
      }
      __syncthreads();
      if (lane >= s_lo && lane < S) {
        float mx = -1e30f;
        for (int t2 = 0; t2 < S; ++t2) mx = fmaxf(mx, lgS[hh][lane][t2]);
        float sm = 0.f;
        for (int t2 = 0; t2 < S; ++t2) { float e = expf(lgS[hh][lane][t2] - mx); lgS[hh][lane][t2] = e; sm += e; }
        float inv = 1.f / sm;
        for (int t2 = 0; t2 < S; ++t2) lgS[hh][lane][t2] *= inv;
      }
      __syncthreads();
      for (int s = s_lo; s < S; ++s) {
        float o = 0.f;
        for (int t2 = 0; t2 < S; ++t2) o += lgS[hh][s][t2] * scr[t2][512 + hh * 64 + lane];
        x[s][hh * 64 + lane] = o;
      }
    }
    __syncthreads();

    // proj + residual into h
    {
      const float* wr = wo + (size_t)tid * 256;
      float acc[9] = {};
      for (int k = 0; k < 256; k += 4) {
        float4 w4 = *(const float4*)(wr + k);
#pragma unroll
        for (int s = 0; s < 9; ++s) {
          if (s >= s_lo && s < S) {
            float4 a4 = *(const float4*)&x[s][k];
            acc[s] += a4.x * w4.x + a4.y * w4.y + a4.z * w4.z + a4.w * w4.w;
          }
        }
      }
#pragma unroll
      for (int s = 0; s < 9; ++s)
        if (s >= s_lo && s < S) h[s][tid] += acc[s] + bol[tid];
    }
    __syncthreads();

    // ln2 -> x (rows [s_lo,S))
    {
      int w = tid >> 6, lane = tid & 63;
      for (int s = w; s < S; s += 4) {
        if (s < s_lo) continue;
        float4 v4 = *(const float4*)&h[s][lane << 2];
        float su = v4.x + v4.y + v4.z + v4.w;
        float sq = v4.x * v4.x + v4.y * v4.y + v4.z * v4.z + v4.w * v4.w;
#pragma unroll
        for (int o = 32; o > 0; o >>= 1) { su += __shfl_down(su, o); sq += __shfl_down(sq, o); }
        su = __shfl(su, 0); sq = __shfl(sq, 0);
        float mu = su * (1.f / 256.f);
        float var = fmaxf(sq * (1.f / 256.f) - mu * mu, 0.f);
        float rs = rsqrtf(var + 1e-5f);
        float4 g4 = *(const float4*)(g2p + (lane << 2));
        float4 bt4 = *(const float4*)(b2p + (lane << 2));
        x[s][(lane << 2) + 0] = (v4.x - mu) * rs * g4.x + bt4.x;
        x[s][(lane << 2) + 1] = (v4.y - mu) * rs * g4.y + bt4.y;
        x[s][(lane << 2) + 2] = (v4.z - mu) * rs * g4.z + bt4.z;
        x[s][(lane << 2) + 3] = (v4.w - mu) * rs * g4.w + bt4.w;
      }
    }
    __syncthreads();

    // ffn1: thread owns mid dims tid+256j, j=0..3 -> scr (relu)
    {
      const float* wr0 = w1l + (size_t)tid * 256;
      const float* wr1 = w1l + (size_t)(tid + 256) * 256;
      const float* wr2 = w1l + (size_t)(tid + 512) * 256;
      const float* wr3 = w1l + (size_t)(tid + 768) * 256;
      float acc[4][9] = {};
      for (int k = 0; k < 256; k += 4) {
        float4 v0 = *(const float4*)(wr0 + k);
        float4 v1 = *(const float4*)(wr1 + k);
        float4 v2 = *(const float4*)(wr2 + k);
        float4 v3 = *(const float4*)(wr3 + k);
#pragma unroll
        for (int s = 0; s < 9; ++s) {
          if (s >= s_lo && s < S) {
            float4 xv = *(const float4*)&x[s][k];
            acc[0][s] += xv.x * v0.x + xv.y * v0.y + xv.z * v0.z + xv.w * v0.w;
            acc[1][s] += xv.x * v1.x + xv.y * v1.y + xv.z * v1.z + xv.w * v1.w;
            acc[2][s] += xv.x * v2.x + xv.y * v2.y + xv.z * v2.z + xv.w * v2.w;
            acc[3][s] += xv.x * v3.x + xv.y * v3.y + xv.z * v3.z + xv.w * v3.w;
          }
        }
      }
#pragma unroll
      for (int j = 0; j < 4; ++j)
#pragma unroll
        for (int s = 0; s < 9; ++s)
          if (s >= s_lo && s < S)
            scr[s][tid + 256 * j] = fmaxf(acc[j][s] + bb1[tid + 256 * j], 0.f);
    }
    __syncthreads();

    // ffn2 + residual into h
    {
      const float* wr = w2l + (size_t)tid * 1024;
      float acc[9] = {};
      for (int k = 0; k < 1024; k += 4) {
        float4 w4 = *(const float4*)(wr + k);
#pragma unroll
        for (int s = 0; s < 9; ++s) {
          if (s >= s_lo && s < S) {
            float4 m4 = *(const float4*)&scr[s][k];
            acc[s] += m4.x * w4.x + m4.y * w4.y + m4.z * w4.z + m4.w * w4.w;
          }
        }
      }
#pragma unroll
      for (int s = 0; s < 9; ++s)
        if (s >= s_lo && s < S) h[s][tid] += acc[s] + bb2[tid];
    }
    __syncthreads();
  }

  // out-LN on h[S-1] -> c_out, lstm layer-0 x input
  {
    float v = h[S - 1][tid];
    float mu = blk_sum(v, s8) * (1.f / 256.f);
    float dd = v - mu;
    float var = blk_sum(dd * dd, s8) * (1.f / 256.f);
    float rs = rsqrtf(var + 1e-5f);
    float y = dd * rs * olng[tid] + olnb[tid];
    c_out[b * 256 + tid] = y;
    lstm_in[(size_t)b * 512 + tid] = y;
  }
}

// ---- LSTM GEMM with fused pointwise epilogue (gate-interleaved Wc) ----
template <int LAST>
__global__ __launch_bounds__(256) void lstmg_k(
    const float* __restrict__ A, const float* __restrict__ W,
    const float* __restrict__ cbias, float* cx, float* li_l, float* li_next,
    const float* __restrict__ c_outp, float* c_fin, unsigned short* cfb,
    float* record) {
  __shared__ float As[2][16][36];
  __shared__ float Ws[2][16][68];
  const int tid = threadIdx.x, tx = tid & 15, ty = tid >> 4;
  const int n0 = blockIdx.x * 64;
  const int lar = tid >> 2, laq = (tid & 3) << 2;
  float4 a4 = make_float4(0.f, 0.f, 0.f, 0.f), w4;
  if (tid < 128) a4 = *(const float4*)(A + (size_t)lar * 512 + laq);
  w4 = *(const float4*)(W + (size_t)(n0 + lar) * 512 + laq);
  float acc[2][4] = {};
  int buf = 0;
  for (int kt = 0; kt < 32; ++kt) {
    if (tid < 128) {
      As[buf][laq + 0][lar] = a4.x; As[buf][laq + 1][lar] = a4.y;
      As[buf][laq + 2][lar] = a4.z; As[buf][laq + 3][lar] = a4.w;
    }
    Ws[buf][laq + 0][lar] = w4.x; Ws[buf][laq + 1][lar] = w4.y;
    Ws[buf][laq + 2][lar] = w4.z; Ws[buf][laq + 3][lar] = w4.w;
    __syncthreads();
    if (kt + 1 < 32) {
      const int k1 = (kt + 1) << 4;
      if (tid < 128) a4 = *(const float4*)(A + (size_t)lar * 512 + k1 + laq);
      w4 = *(const float4*)(W + (size_t)(n0 + lar) * 512 + k1 + laq);
    }
#pragma unroll
    for (int kk = 0; kk < 16; ++kk) {
      float2 av = *(const float2*)&As[buf][kk][ty << 1];
      float4 wv = *(const float4*)&Ws[buf][kk][tx << 2];
      acc[0][0] += av.x * wv.x; acc[0][1] += av.x * wv.y; acc[0][2] += av.x * wv.z; acc[0][3] += av.x * wv.w;
      acc[1][0] += av.y * wv.x; acc[1][1] += av.y * wv.y; acc[1][2] += av.y * wv.z; acc[1][3] += av.y * wv.w;
    }
    buf ^= 1;
  }
  const int d = (n0 >> 2) + tx;
#pragma unroll
  for (int i = 0; i < 2; ++i) {
    int b = ty * 2 + i;
    float gi = acc[i][0] + cbias[n0 + tx * 4 + 0];
    float gf = acc[i][1] + cbias[n0 + tx * 4 + 1];
    float gg = acc[i][2] + cbias[n0 + tx * 4 + 2];
    float go = acc[i][3] + cbias[n0 + tx * 4 + 3];
    float c = sigf(gf) * cx[b * 256 + d] + sigf(gi) * tanhf(gg);
    float hN = sigf(go) * tanhf(c);
    cx[b * 256 + d] = c;
    li_l[(size_t)b * 512 + 256 + d] = hN;
    if constexpr (LAST) {
      record[b * 256 + d] = hN;
      float cf = c_outp[b * 256 + d] + hN;
      c_fin[b * 256 + d] = cf;
      cfb[b * 256 + d] = f2bf(cf);
    } else {
      li_next[(size_t)b * 512 + d] = hN;
    }
  }
}

// ---- generic tiled GEMM (used for read/write params), TM=32 TN=64 ----
__global__ __launch_bounds__(256) void gemm_k(
    const float* __restrict__ A, const float* __restrict__ W,
    const float* __restrict__ bias, float* C, int M, int N, int K) {
  __shared__ float As[2][16][36];
  __shared__ float Ws[2][16][68];
  const int tid = threadIdx.x, tx = tid & 15, ty = tid >> 4;
  const int m0 = blockIdx.y * 32, n0 = blockIdx.x * 64;
  const int lar = tid >> 2, laq = (tid & 3) << 2;
  const int KT = K >> 4;
  float4 a4 = make_float4(0.f, 0.f, 0.f, 0.f), w4 = make_float4(0.f, 0.f, 0.f, 0.f);
  if (tid < 128) {
    const int m = m0 + lar;
    if (m < M) a4 = *(const float4*)(A + (size_t)m * K + laq);
  }
  { const int n = n0 + lar; if (n < N) w4 = *(const float4*)(W + (size_t)n * K + laq); }
  float acc[2][4] = {};
  int buf = 0;
  for (int kt = 0; kt < KT; ++kt) {
    if (tid < 128) {
      As[buf][laq + 0][lar] = a4.x; As[buf][laq + 1][lar] = a4.y;
      As[buf][laq + 2][lar] = a4.z; As[buf][laq + 3][lar] = a4.w;
    }
    Ws[buf][laq + 0][lar] = w4.x; Ws[buf][laq + 1][lar] = w4.y;
    Ws[buf][laq + 2][lar] = w4.z; Ws[buf][laq + 3][lar] = w4.w;
    __syncthreads();
    if (kt + 1 < KT) {
      const int k1 = (kt + 1) << 4;
      a4 = make_float4(0.f, 0.f, 0.f, 0.f); w4 = make_float4(0.f, 0.f, 0.f, 0.f);
      if (tid < 128) { const int m = m0 + lar; if (m < M) a4 = *(const float4*)(A + (size_t)m * K + k1 + laq); }
      { const int n = n0 + lar; if (n < N) w4 = *(const float4*)(W + (size_t)n * K + k1 + laq); }
    }
#pragma unroll
    for (int kk = 0; kk < 16; ++kk) {
      float2 av = *(const float2*)&As[buf][kk][ty << 1];
      float4 wv = *(const float4*)&Ws[buf][kk][tx << 2];
      acc[0][0] += av.x * wv.x; acc[0][1] += av.x * wv.y; acc[0][2] += av.x * wv.z; acc[0][3] += av.x * wv.w;
      acc[1][0] += av.y * wv.x; acc[1][1] += av.y * wv.y; acc[1][2] += av.y * wv.z; acc[1][3] += av.y * wv.w;
    }
    buf ^= 1;
  }
#pragma unroll
  for (int i = 0; i < 2; ++i) {
    const int m = m0 + ty * 2 + i;
    if (m >= M) continue;
#pragma unroll
    for (int j = 0; j < 4; ++j) {
      const int n = n0 + tx * 4 + j;
      if (n >= N) continue;
      C[(size_t)m * N + n] = acc[i][j] + bias[n];
    }
  }
}

// ---- head: logits = c_fin(bf16) @ head_W(bf16)^T + head_b via MFMA ----
__global__ __launch_bounds__(256) void head_k(const unsigned short* __restrict__ Wh,
                                              const unsigned short* __restrict__ Ah,
                                              const float* __restrict__ hb,
                                              float* __restrict__ out) {
  const int tid = threadIdx.x;
  const int w = tid >> 6, l = tid & 63;
  const int r = l & 15, q = l >> 4;
  const int n = blockIdx.x * 64 + w * 16 + r;
  const int nc = n < VV ? n : VV - 1;
  const short* Ap = (const short*)Ah;
  const short* Wp = (const short*)Wh + (size_t)nc * 256;
  short8 a0[8], a1[8], bf[8];
#pragma unroll
  for (int kt = 0; kt < 8; ++kt) {
    a0[kt] = *(const short8*)(Ap + r * 256 + kt * 32 + q * 8);
    a1[kt] = *(const short8*)(Ap + (16 + r) * 256 + kt * 32 + q * 8);
    bf[kt] = *(const short8*)(Wp + kt * 32 + q * 8);
  }
  f32x4 acc0 = {0.f, 0.f, 0.f, 0.f}, acc1 = {0.f, 0.f, 0.f, 0.f};
#pragma unroll
  for (int kt = 0; kt < 8; ++kt) {
    acc0 = __builtin_amdgcn_mfma_f32_16x16x32_bf16(a0[kt], bf[kt], acc0, 0, 0, 0);
    acc1 = __builtin_amdgcn_mfma_f32_16x16x32_bf16(a1[kt], bf[kt], acc1, 0, 0, 0);
  }
  if (n < VV) {
    float bb = hb[n];
#pragma unroll
    for (int e = 0; e < 4; ++e) {
      int m = q * 4 + e;
      out[(size_t)m * VV + n] = acc0[e] + bb;
      out[(size_t)(16 + m) * VV + n] = acc1[e] + bb;
    }
  }
}

// ---- pass A over bf16 memory: dots + row norms ----
__global__ __launch_bounds__(256) void passA_k(const unsigned short* __restrict__ mem,
                                               const float* __restrict__ rpwp,
                                               float* __restrict__ dr,
                                               float* __restrict__ dw,
                                               float* __restrict__ nrm) {
  __shared__ float kr[256], kw[256];
  int b = blockIdx.y, tid = threadIdx.x;
  kr[tid] = rpwp[(size_t)b * 1036 + tid];
  kw[tid] = rpwp[(size_t)b * 1036 + 262 + tid];
  __syncthreads();
  int w = tid >> 6, lane = tid & 63;
  float4 kr4 = *(float4*)&kr[lane * 4];
  float4 kw4 = *(float4*)&kw[lane * 4];
  int n0 = blockIdx.x * 16 + w * 4;
  for (int rr = 0; rr < 4; ++rr) {
    int n = n0 + rr;
    const unsigned short* row = mem + ((size_t)b * NN + n) * 256;
    uint2 p = *(const uint2*)(row + lane * 4);
    float m0 = bf2f(p.x & 0xffffu), m1 = bf2f(p.x >> 16);
    float m2 = bf2f(p.y & 0xffffu), m3 = bf2f(p.y >> 16);
    float pr = m0 * kr4.x + m1 * kr4.y + m2 * kr4.z + m3 * kr4.w;
    float pw = m0 * kw4.x + m1 * kw4.y + m2 * kw4.z + m3 * kw4.w;
    float pn = m0 * m0 + m1 * m1 + m2 * m2 + m3 * m3;
#pragma unroll
    for (int o = 32; o > 0; o >>= 1) {
      pr += __shfl_down(pr, o); pw += __shfl_down(pw, o); pn += __shfl_down(pn, o);
    }
    if (lane == 0) {
      dr[(size_t)b * NN + n] = pr;
      dw[(size_t)b * NN + n] = pw;
      nrm[(size_t)b * NN + n] = pn;
    }
  }
}

// ---- addressing ----
__global__ __launch_bounds__(256) void addr_k(const float* __restrict__ dr,
                                              const float* __restrict__ dw,
                                              const float* __restrict__ nrm,
                                              const float* __restrict__ rpwp,
                                              float* rw, float* ww,
                                              float* __restrict__ ea,
                                              float* __restrict__ rvec) {
  __shared__ float wg[4096];
  __shared__ float s8[8];
  int head = blockIdx.x & 1, b = blockIdx.x >> 1;
  int tid = threadIdx.x;
  const float* p = rpwp + (size_t)b * 1036 + (head ? 262 : 0);
  const float* dot = (head ? dw : dr) + (size_t)b * NN;
  const float* n2 = nrm + (size_t)b * NN;
  float* wout = (head ? ww : rw) + (size_t)b * NN;

  float kv = p[tid];
  float kn = sqrtf(blk_sum(kv * kv, s8)) + EPS_;
  float beta = p[256], gate = p[257], sh0 = p[258], sh1 = p[259], sh2 = p[260], gamma = p[261];
  float spb = softplusf_(beta);
  float g = sigf(gate);
  float mx3 = fmaxf(sh0, fmaxf(sh1, sh2));
  float e0 = expf(sh0 - mx3), e1 = expf(sh1 - mx3), e2 = expf(sh2 - mx3);
  float esum = e0 + e1 + e2;
  float s0 = e0 / esum, s1 = e1 / esum, s2 = e2 / esum;
  float gp = 1.f + softplusf_(gamma);

  float l[16];
  float lmax = -1e30f;
#pragma unroll
  for (int i = 0; i < 16; ++i) {
    int n = tid + i * 256;
    float cs = dot[n] / ((sqrtf(n2[n]) + EPS_) * kn);
    l[i] = spb * cs;
    lmax = fmaxf(lmax, l[i]);
  }
  float Mx = blk_max(lmax, s8);
  float es = 0.f;
#pragma unroll
  for (int i = 0; i < 16; ++i) { l[i] = expf(l[i] - Mx); es += l[i]; }
  float SS = blk_sum(es, s8);
  float inv = 1.f / SS;
#pragma unroll
  for (int i = 0; i < 16; ++i) {
    int n = tid + i * 256;
    wg[n] = g * l[i] * inv + (1.f - g) * wout[n];
  }
  __syncthreads();
  float wt[16];
  float wsum = 0.f;
#pragma unroll
  for (int i = 0; i < 16; ++i) {
    int n = tid + i * 256;
    float sh = s0 * wg[(n + 1) & 4095] + s1 * wg[n] + s2 * wg[(n + 4095) & 4095];
    wt[i] = powf(sh + EPS_, gp);
    wsum += wt[i];
  }
  float WS = blk_sum(wsum, s8) + EPS_;
  float winv = 1.f / WS;
#pragma unroll
  for (int i = 0; i < 16; ++i) wout[tid + i * 256] = wt[i] * winv;

  if (head) {
    ea[(size_t)b * 512 + tid] = sigf(p[262 + tid]);
    ea[(size_t)b * 512 + 256 + tid] = tanhf(p[518 + tid]);
  } else {
    rvec[(size_t)b * 256 + tid] = 0.f;
  }
}

// ---- pass B over bf16 memory: erase/add + fused r = rw . mem_new ----
template <int FIRST>
__global__ __launch_bounds__(256) void passB_k(unsigned short* mem, const float* __restrict__ ww,
                                               const float* __restrict__ rw,
                                               const float* __restrict__ ea,
                                               float* __restrict__ rvec) {
  __shared__ float eS[256], aS[256];
  __shared__ float rred[4][256];
  int b = blockIdx.y, tid = threadIdx.x;
  eS[tid] = ea[(size_t)b * 512 + tid];
  aS[tid] = ea[(size_t)b * 512 + 256 + tid];
  __syncthreads();
  int w = tid >> 6, lane = tid & 63;
  float4 e4 = *(float4*)&eS[lane * 4];
  float4 a4 = *(float4*)&aS[lane * 4];
  float4 racc = make_float4(0.f, 0.f, 0.f, 0.f);
  int n0 = blockIdx.x * 128 + w * 32;
  for (int rr = 0; rr < 32; ++rr) {
    int n = n0 + rr;
    float wt = ww[(size_t)b * NN + n];
    float rwv = rw[(size_t)b * NN + n];
    unsigned short* row = mem + ((size_t)b * NN + n) * 256;
    float m0, m1, m2, m3;
    if (FIRST) {
      m0 = wt * a4.x; m1 = wt * a4.y; m2 = wt * a4.z; m3 = wt * a4.w;
    } else {
      uint2 p = *(const uint2*)(row + lane * 4);
      m0 = bf2f(p.x & 0xffffu) * (1.f - wt * e4.x) + wt * a4.x;
      m1 = bf2f(p.x >> 16) * (1.f - wt * e4.y) + wt * a4.y;
      m2 = bf2f(p.y & 0xffffu) * (1.f - wt * e4.z) + wt * a4.z;
      m3 = bf2f(p.y >> 16) * (1.f - wt * e4.w) + wt * a4.w;
    }
    uint2 pk;
    pk.x = (unsigned)f2bf(m0) | ((unsigned)f2bf(m1) << 16);
    pk.y = (unsigned)f2bf(m2) | ((unsigned)f2bf(m3) << 16);
    *(uint2*)(row + lane * 4) = pk;
    racc.x += rwv * m0; racc.y += rwv * m1; racc.z += rwv * m2; racc.w += rwv * m3;
  }
  rred[w][lane * 4 + 0] = racc.x;
  rred[w][lane * 4 + 1] = racc.y;
  rred[w][lane * 4 + 2] = racc.z;
  rred[w][lane * 4 + 3] = racc.w;
  __syncthreads();
  float s = rred[0][tid] + rred[1][tid] + rred[2][tid] + rred[3][tid];
  atomicAdd(rvec + (size_t)b * 256 + tid, s);
}

extern "C" void kernel_launch(void* const* d_in, const int* in_sizes, int n_in,
                              void* d_out, int out_size, void* d_ws, size_t ws_size,
                              hipStream_t stream) {
  const int* tokens = (const int*)d_in[0];
  const float* emb_W = (const float*)d_in[1];
  const float* read_gate_W = (const float*)d_in[2];
  const float* read_gate_b = (const float*)d_in[3];
  const float* film_W = (const float*)d_in[4];
  const float* film_b = (const float*)d_in[5];
  const float* t_Wqkv = (const float*)d_in[6];
  const float* t_bqkv = (const float*)d_in[7];
  const float* t_Wo = (const float*)d_in[8];
  const float* t_bo = (const float*)d_in[9];
  const float* t_ln1_g = (const float*)d_in[10];
  const float* t_ln1_b = (const float*)d_in[11];
  const float* t_ln2_g = (const float*)d_in[12];
  const float* t_ln2_b = (const float*)d_in[13];
  const float* t_W1 = (const float*)d_in[14];
  const float* t_b1 = (const float*)d_in[15];
  const float* t_W2 = (const float*)d_in[16];
  const float* t_b2 = (const float*)d_in[17];
  const float* out_ln_g = (const float*)d_in[18];
  const float* out_ln_b = (const float*)d_in[19];
  const float* lstm_Wih = (const float*)d_in[20];
  const float* lstm_Whh = (const float*)d_in[21];
  const float* lstm_bih = (const float*)d_in[22];
  const float* lstm_bhh = (const float*)d_in[23];
  const float* head_W = (const float*)d_in[24];
  const float* head_b = (const float*)d_in[25];
  const float* read_W = (const float*)d_in[26];
  const float* read_b = (const float*)d_in[27];
  const float* write_W = (const float*)d_in[28];
  const float* write_b = (const float*)d_in[29];
  float* out = (float*)d_out;

  float* ws = (float*)d_ws;
  size_t off = 0;
  // ---- zero-initialized region ----
  float* read_w = ws + off; off += (size_t)BB * NN;
  float* write_w = ws + off; off += (size_t)BB * NN;
  float* record = ws + off; off += BB * DD;
  float* cx = ws + off; off += 2 * BB * DD;
  float* lstm_in = ws + off; off += 2 * BB * 512;
  float* r_vec = ws + off; off += BB * DD;
  float* dot_r = ws + off; off += (size_t)BB * NN;
  float* dot_w = ws + off; off += (size_t)BB * NN;
  float* norm2 = ws + off; off += (size_t)BB * NN;
  size_t zero_floats = off;
  // ---- not zeroed ----
  unsigned short* memory = (unsigned short*)(ws + off); off += (size_t)BB * NN * DD / 2;
  float* hpe = ws + off; off += 9 * BB * DD;
  float* c_out = ws + off; off += BB * DD;
  float* c_fin = ws + off; off += BB * DD;
  float* rpwp = ws + off; off += BB * 1036;
  float* ea = ws + off; off += BB * 2 * DD;
  float* Wc2 = ws + off; off += 2 * 1024 * 512;
  float* cb2 = ws + off; off += 2 * 1024;
  float* Wrw = ws + off; off += 1036 * 256;
  float* brw = ws + off; off += 1040;
  unsigned short* Wh = (unsigned short*)(ws + off); off += (size_t)VV * 256 / 2;
  unsigned short* cfb = (unsigned short*)(ws + off); off += BB * DD / 2;
  if (ws_size < off * sizeof(float)) return;

  (void)hipMemsetAsync(ws, 0, zero_floats * sizeof(float), stream);
  init_k<<<32, 256, 0, stream>>>(read_w, write_w, hpe);
  cvtw_k<<<(VV * 256 / 4 + 255) / 256, 256, 0, stream>>>(head_W, Wh, VV * 256 / 4);
  catlstm_k<<<4096, 256, 0, stream>>>(lstm_Wih, lstm_Whh, lstm_bih, lstm_bhh, Wc2, cb2);
  catrw_k<<<1036, 256, 0, stream>>>(read_W, read_b, write_W, write_b, Wrw, brw);

  for (int t = 0; t < TT; ++t) {
    tf_k<<<BB, 256, 0, stream>>>(tokens, emb_W, read_gate_W, read_gate_b, film_W, film_b,
                                 record, r_vec, t_Wqkv, t_bqkv, t_Wo, t_bo,
                                 t_ln1_g, t_ln1_b, t_ln2_g, t_ln2_b,
                                 t_W1, t_b1, t_W2, t_b2, out_ln_g, out_ln_b,
                                 hpe, c_out, lstm_in, t);
    lstmg_k<0><<<16, 256, 0, stream>>>(lstm_in, Wc2, cb2, cx, lstm_in,
                                       lstm_in + (size_t)BB * 512, nullptr, nullptr, nullptr, nullptr);
    lstmg_k<1><<<16, 256, 0, stream>>>(lstm_in + (size_t)BB * 512, Wc2 + (size_t)1024 * 512,
                                       cb2 + 1024, cx + BB * DD, lstm_in + (size_t)BB * 512,
                                       nullptr, c_out, c_fin, cfb, record);
    head_k<<<(VV + 63) / 64, 256, 0, stream>>>(Wh, cfb, head_b, out + (size_t)t * BB * VV);

    if (t < TT - 1) {
      gemm_k<<<dim3(17, 1), 256, 0, stream>>>(c_fin, Wrw, brw, rpwp, BB, 1036, 256);
      if (t > 0)
        passA_k<<<dim3(NN / 16, BB), 256, 0, stream>>>(memory, rpwp, dot_r, dot_w, norm2);
      addr_k<<<2 * BB, 256, 0, stream>>>(dot_r, dot_w, norm2, rpwp, read_w, write_w, ea, r_vec);
      if (t == 0)
        passB_k<1><<<dim3(NN / 128, BB), 256, 0, stream>>>(memory, write_w, read_w, ea, r_vec);
      else
        passB_k<0><<<dim3(NN / 128, BB), 256, 0, stream>>>(memory, write_w, read_w, ea, r_vec);
    }
  }
}

// Round 4
// 2855.263 us; speedup vs baseline: 1.4412x; 1.4412x over previous
//
#include <hip/hip_runtime.h>
#include <math.h>

#define TT 8
#define BB 32
#define VV 50257
#define DD 256
#define NN 4096
#define EPS_ 1e-12f

typedef __attribute__((ext_vector_type(8))) short short8;
typedef __attribute__((ext_vector_type(4))) float f32x4;

__device__ __forceinline__ float sigf(float x) { return 1.f / (1.f + expf(-x)); }
__device__ __forceinline__ float softplusf_(float x) { return fmaxf(x, 0.f) + log1pf(expf(-fabsf(x))); }
__device__ __forceinline__ unsigned short f2bf(float f) {
  union { float f; unsigned u; } c; c.f = f;
  return (unsigned short)((c.u + 0x7FFFu + ((c.u >> 16) & 1u)) >> 16);
}
__device__ __forceinline__ float bf2f(unsigned u16) {
  union { unsigned u; float f; } c; c.u = u16 << 16; return c.f;
}

// ---- block reductions (256-thread blocks only) ----
__device__ __forceinline__ float blk_sum(float v, float* s) {
#pragma unroll
  for (int o = 32; o > 0; o >>= 1) v += __shfl_down(v, o);
  __syncthreads();
  if ((threadIdx.x & 63) == 0) s[threadIdx.x >> 6] = v;
  __syncthreads();
  return s[0] + s[1] + s[2] + s[3];
}
__device__ __forceinline__ float blk_max(float v, float* s) {
#pragma unroll
  for (int o = 32; o > 0; o >>= 1) v = fmaxf(v, __shfl_down(v, o));
  __syncthreads();
  if ((threadIdx.x & 63) == 0) s[threadIdx.x >> 6] = v;
  __syncthreads();
  return fmaxf(fmaxf(s[0], s[1]), fmaxf(s[2], s[3]));
}

// ---- one-time init: one-hot weights + hpe row 0 (zeros + pe[0]) ----
__global__ void init_k(float* rw, float* ww, float* hpe) {
  int i = blockIdx.x * 256 + threadIdx.x;
  if (i < BB) { rw[(size_t)i * NN] = 1.f; ww[(size_t)i * NN] = 1.f; }
  if (i < BB * DD) hpe[i] = (i & 1) ? 1.f : 0.f;
}

// ---- head_W f32 -> bf16 ----
__global__ void cvtw_k(const float* __restrict__ W, unsigned short* __restrict__ Wh, int n4) {
  int i = blockIdx.x * 256 + threadIdx.x;
  if (i >= n4) return;
  float4 v = *(const float4*)(W + (size_t)i * 4);
  unsigned u0 = (unsigned)f2bf(v.x) | ((unsigned)f2bf(v.y) << 16);
  unsigned u1 = (unsigned)f2bf(v.z) | ((unsigned)f2bf(v.w) << 16);
  uint2 p; p.x = u0; p.y = u1;
  *(uint2*)(Wh + (size_t)i * 4) = p;
}

// ---- tiled transpose: out[k][ocol0+n] = in[n][k]; in is Nr x Kc row-major ----
__global__ __launch_bounds__(256) void tr_k(const float* __restrict__ in, float* __restrict__ out,
                                            int Nr, int Kc, int ostride, int ocol0) {
  __shared__ float tile[32][33];
  int k0 = blockIdx.x * 32, n0 = blockIdx.y * 32;
  int tx = threadIdx.x & 31, ty = threadIdx.x >> 5;
#pragma unroll
  for (int j = 0; j < 4; ++j) {
    int n = n0 + ty + 8 * j;
    if (n < Nr && k0 + tx < Kc) tile[ty + 8 * j][tx] = in[(size_t)n * Kc + k0 + tx];
  }
  __syncthreads();
#pragma unroll
  for (int j = 0; j < 4; ++j) {
    int k = k0 + ty + 8 * j;
    if (k < Kc && n0 + tx < Nr) out[(size_t)k * ostride + ocol0 + n0 + tx] = tile[tx][ty + 8 * j];
  }
}

// ---- combined LSTM weights, gate-interleaved rows n' = d*4+gate, K=512 ----
__global__ void catlstm_k(const float* __restrict__ Wih, const float* __restrict__ Whh,
                          const float* __restrict__ bih, const float* __restrict__ bhh,
                          float* __restrict__ Wc, float* __restrict__ cb) {
  int i = blockIdx.x * 256 + threadIdx.x;
  if (i >= 2 * 1024 * 512) return;
  int k = i & 511, np = (i >> 9) & 1023, l = i >> 19;
  int d = np >> 2, gate = np & 3;
  int src = gate * 256 + d;
  Wc[i] = (k < 256) ? Wih[((size_t)l * 1024 + src) * 256 + k]
                    : Whh[((size_t)l * 1024 + src) * 256 + (k - 256)];
  if (k == 0) cb[l * 1024 + np] = bih[l * 1024 + src] + bhh[l * 1024 + src];
}

// ---- combined read/write param weights (1036 x 256) + bias ----
__global__ void catrw_k(const float* __restrict__ rW, const float* __restrict__ rb,
                        const float* __restrict__ wW, const float* __restrict__ wb,
                        float* __restrict__ Wrw, float* __restrict__ brw) {
  int i = blockIdx.x * 256 + threadIdx.x;
  if (i >= 1036 * 256) return;
  int k = i & 255, n = i >> 8;
  Wrw[i] = (n < 262) ? rW[(size_t)n * 256 + k] : wW[(size_t)(n - 262) * 256 + k];
  if (k == 0) brw[n] = (n < 262) ? rb[n] : wb[n - 262];
}

// ---- xin: 4 batches/block, FiLM+gate via transposed FRT [256][768], +PE ----
__global__ __launch_bounds__(256) void xin2_k(
    const int* __restrict__ tokens, const float* __restrict__ embW,
    const float* __restrict__ FRT, const float* __restrict__ filmb,
    const float* __restrict__ rgb, const float* __restrict__ record,
    const float* __restrict__ rvec, float* __restrict__ hpe, int t) {
  __shared__ float As[256][4];
  const int tid = threadIdx.x, b0 = blockIdx.x * 4;
  const int rr = tid >> 6, cc = (tid & 63) * 4;
  {
    float4 u = *(const float4*)(record + (size_t)(b0 + rr) * 256 + cc);
    As[cc + 0][rr] = u.x; As[cc + 1][rr] = u.y; As[cc + 2][rr] = u.z; As[cc + 3][rr] = u.w;
  }
  __syncthreads();
  float a1[4] = {}, a2[4] = {}, a3[4] = {};
  const float* w1p = FRT + tid;
  const float* w2p = FRT + 256 + tid;
  const float* w3p = FRT + 512 + tid;
#pragma unroll 4
  for (int k = 0; k < 256; ++k) {
    float4 a = *(const float4*)&As[k][0];
    float w1 = w1p[(size_t)k * 768], w2 = w2p[(size_t)k * 768], w3 = w3p[(size_t)k * 768];
    a1[0] += a.x * w1; a1[1] += a.y * w1; a1[2] += a.z * w1; a1[3] += a.w * w1;
    a2[0] += a.x * w2; a2[1] += a.y * w2; a2[2] += a.z * w2; a2[3] += a.w * w2;
    a3[0] += a.x * w3; a3[1] += a.y * w3; a3[2] += a.z * w3; a3[3] += a.w * w3;
  }
  float ang = (float)(t + 1) * expf(-logf(10000.f) * (float)(tid & ~1) / 256.f);
  float pe = (tid & 1) ? cosf(ang) : sinf(ang);
  float fb1 = filmb[tid], fb2 = filmb[256 + tid], rb_ = rgb[tid];
#pragma unroll
  for (int i = 0; i < 4; ++i) {
    int b = b0 + i;
    float gam = 1.f + tanhf(a1[i] + fb1);
    float bet = a2[i] + fb2;
    float rg = sigf(a3[i] + rb_);
    int tok = tokens[t * BB + b];
    float emb = embW[(size_t)tok * 256 + tid];
    hpe[((size_t)(t + 1) * BB + b) * 256 + tid] = gam * emb + bet + rg * rvec[b * 256 + tid] + pe;
  }
}

// ---- qkv with fused LN1: 8 rows x 256-col tile; WT [256][768] ----
__global__ __launch_bounds__(256) void qkv_k(
    const float* __restrict__ Asrc, const float* __restrict__ WT,
    const float* __restrict__ bq, const float* __restrict__ g1, const float* __restrict__ b1,
    float* __restrict__ qkv) {
  __shared__ float As[256][8];
  __shared__ float muS[8], rsS[8];
  const int tid = threadIdx.x;
  const int m0 = blockIdx.y * 8;
  const int n = blockIdx.x * 256 + tid;
  const int r = tid >> 5, c0 = (tid & 31) * 8;
  float v[8];
  {
    const float* ap = Asrc + (size_t)(m0 + r) * 256 + c0;
    float4 u0 = *(const float4*)ap, u1 = *(const float4*)(ap + 4);
    v[0] = u0.x; v[1] = u0.y; v[2] = u0.z; v[3] = u0.w;
    v[4] = u1.x; v[5] = u1.y; v[6] = u1.z; v[7] = u1.w;
    float s1 = 0.f, s2 = 0.f;
#pragma unroll
    for (int i = 0; i < 8; ++i) { s1 += v[i]; s2 += v[i] * v[i]; }
#pragma unroll
    for (int o = 16; o > 0; o >>= 1) { s1 += __shfl_xor(s1, o); s2 += __shfl_xor(s2, o); }
    if ((tid & 31) == 0) {
      float mu = s1 * (1.f / 256.f);
      float var = fmaxf(s2 * (1.f / 256.f) - mu * mu, 0.f);
      muS[r] = mu; rsS[r] = rsqrtf(var + 1e-5f);
    }
  }
  __syncthreads();
  {
    float mu = muS[r], rs = rsS[r];
#pragma unroll
    for (int i = 0; i < 8; ++i) As[c0 + i][r] = (v[i] - mu) * rs * g1[c0 + i] + b1[c0 + i];
  }
  __syncthreads();
  float acc[8] = {};
  const float* wp = WT + n;
#pragma unroll 8
  for (int k = 0; k < 256; ++k) {
    float w = wp[(size_t)k * 768];
    float4 a0 = *(const float4*)&As[k][0];
    float4 a1 = *(const float4*)&As[k][4];
    acc[0] += a0.x * w; acc[1] += a0.y * w; acc[2] += a0.z * w; acc[3] += a0.w * w;
    acc[4] += a1.x * w; acc[5] += a1.y * w; acc[6] += a1.z * w; acc[7] += a1.w * w;
  }
  float bb = bq[n];
#pragma unroll
  for (int i = 0; i < 8; ++i) qkv[(size_t)(m0 + i) * 768 + n] = acc[i] + bb;
}

// ---- proj + residual + LN2: full 256-wide row per block, 8 rows ----
__global__ __launch_bounds__(256) void proj_k(
    const float* __restrict__ Asrc, const float* __restrict__ WT,
    const float* __restrict__ bo, const float* __restrict__ resid,
    float* __restrict__ hout, const float* __restrict__ g2, const float* __restrict__ b2,
    float* __restrict__ x2) {
  __shared__ float As[256][8];
  __shared__ float red1[8][4], red2[8][4], muS[8], rsS[8];
  const int tid = threadIdx.x, m0 = blockIdx.x * 8;
  const int r = tid >> 5, c0 = (tid & 31) * 8;
  {
    const float* ap = Asrc + (size_t)(m0 + r) * 256 + c0;
    float4 u0 = *(const float4*)ap, u1 = *(const float4*)(ap + 4);
    As[c0 + 0][r] = u0.x; As[c0 + 1][r] = u0.y; As[c0 + 2][r] = u0.z; As[c0 + 3][r] = u0.w;
    As[c0 + 4][r] = u1.x; As[c0 + 5][r] = u1.y; As[c0 + 6][r] = u1.z; As[c0 + 7][r] = u1.w;
  }
  __syncthreads();
  float acc[8] = {};
  const float* wp = WT + tid;
#pragma unroll 8
  for (int k = 0; k < 256; ++k) {
    float w = wp[(size_t)k * 256];
    float4 a0 = *(const float4*)&As[k][0];
    float4 a1 = *(const float4*)&As[k][4];
    acc[0] += a0.x * w; acc[1] += a0.y * w; acc[2] += a0.z * w; acc[3] += a0.w * w;
    acc[4] += a1.x * w; acc[5] += a1.y * w; acc[6] += a1.z * w; acc[7] += a1.w * w;
  }
  float hv[8];
  float bb = bo[tid];
#pragma unroll
  for (int i = 0; i < 8; ++i) {
    hv[i] = acc[i] + bb + resid[(size_t)(m0 + i) * 256 + tid];
    hout[(size_t)(m0 + i) * 256 + tid] = hv[i];
  }
  const int wv = tid >> 6, lane = tid & 63;
#pragma unroll
  for (int i = 0; i < 8; ++i) {
    float s1 = hv[i], s2 = hv[i] * hv[i];
#pragma unroll
    for (int o = 32; o > 0; o >>= 1) { s1 += __shfl_down(s1, o); s2 += __shfl_down(s2, o); }
    if (lane == 0) { red1[i][wv] = s1; red2[i][wv] = s2; }
  }
  __syncthreads();
  if (tid < 8) {
    float s1 = red1[tid][0] + red1[tid][1] + red1[tid][2] + red1[tid][3];
    float s2 = red2[tid][0] + red2[tid][1] + red2[tid][2] + red2[tid][3];
    float mu = s1 * (1.f / 256.f);
    float var = fmaxf(s2 * (1.f / 256.f) - mu * mu, 0.f);
    muS[tid] = mu; rsS[tid] = rsqrtf(var + 1e-5f);
  }
  __syncthreads();
  float g = g2[tid], be = b2[tid];
#pragma unroll
  for (int i = 0; i < 8; ++i)
    x2[(size_t)(m0 + i) * 256 + tid] = (hv[i] - muS[i]) * rsS[i] * g + be;
}

// ---- ffn1 (relu): 8 rows x 256-col tile of N=1024; WT [256][1024] ----
__global__ __launch_bounds__(256) void ffn1_k(
    const float* __restrict__ x2, const float* __restrict__ WT,
    const float* __restrict__ b1, float* __restrict__ mid) {
  __shared__ float As[256][8];
  const int tid = threadIdx.x;
  const int m0 = blockIdx.y * 8;
  const int n = blockIdx.x * 256 + tid;
  const int r = tid >> 5, c0 = (tid & 31) * 8;
  {
    const float* ap = x2 + (size_t)(m0 + r) * 256 + c0;
    float4 u0 = *(const float4*)ap, u1 = *(const float4*)(ap + 4);
    As[c0 + 0][r] = u0.x; As[c0 + 1][r] = u0.y; As[c0 + 2][r] = u0.z; As[c0 + 3][r] = u0.w;
    As[c0 + 4][r] = u1.x; As[c0 + 5][r] = u1.y; As[c0 + 6][r] = u1.z; As[c0 + 7][r] = u1.w;
  }
  __syncthreads();
  float acc[8] = {};
  const float* wp = WT + n;
#pragma unroll 8
  for (int k = 0; k < 256; ++k) {
    float w = wp[(size_t)k * 1024];
    float4 a0 = *(const float4*)&As[k][0];
    float4 a1 = *(const float4*)&As[k][4];
    acc[0] += a0.x * w; acc[1] += a0.y * w; acc[2] += a0.z * w; acc[3] += a0.w * w;
    acc[4] += a1.x * w; acc[5] += a1.y * w; acc[6] += a1.z * w; acc[7] += a1.w * w;
  }
  float bb = b1[n];
#pragma unroll
  for (int i = 0; i < 8; ++i)
    mid[(size_t)(m0 + i) * 1024 + n] = fmaxf(acc[i] + bb, 0.f);
}

// ---- ffn2 + residual (+optional out-LN): 4 rows, full 256-wide; WT [1024][256] ----
template <int OLN>
__global__ __launch_bounds__(256) void ffn2_k(
    const float* __restrict__ mid, const float* __restrict__ WT,
    const float* __restrict__ b2, const float* __restrict__ resid,
    float* __restrict__ hout, const float* __restrict__ olng,
    const float* __restrict__ olnb, float* __restrict__ c_out,
    float* __restrict__ lstm_in) {
  __shared__ float As[1024][4];
  __shared__ float red1[4][4], red2[4][4], muS[4], rsS[4];
  const int tid = threadIdx.x, m0 = blockIdx.x * 4;
  const int rr = tid >> 6, cc = (tid & 63) * 16;
  {
    const float* ap = mid + (size_t)(m0 + rr) * 1024 + cc;
#pragma unroll
    for (int i = 0; i < 16; i += 4) {
      float4 u = *(const float4*)(ap + i);
      As[cc + i + 0][rr] = u.x; As[cc + i + 1][rr] = u.y;
      As[cc + i + 2][rr] = u.z; As[cc + i + 3][rr] = u.w;
    }
  }
  __syncthreads();
  float acc[4] = {};
  const float* wp = WT + tid;
#pragma unroll 8
  for (int k = 0; k < 1024; ++k) {
    float w = wp[(size_t)k * 256];
    float4 a = *(const float4*)&As[k][0];
    acc[0] += a.x * w; acc[1] += a.y * w; acc[2] += a.z * w; acc[3] += a.w * w;
  }
  float bb = b2[tid];
  float hv[4];
#pragma unroll
  for (int i = 0; i < 4; ++i) {
    hv[i] = acc[i] + bb + resid[(size_t)(m0 + i) * 256 + tid];
    hout[(size_t)(m0 + i) * 256 + tid] = hv[i];
  }
  if constexpr (OLN) {
    const int wv = tid >> 6, lane = tid & 63;
#pragma unroll
    for (int i = 0; i < 4; ++i) {
      float s1 = hv[i], s2 = hv[i] * hv[i];
#pragma unroll
      for (int o = 32; o > 0; o >>= 1) { s1 += __shfl_down(s1, o); s2 += __shfl_down(s2, o); }
      if (lane == 0) { red1[i][wv] = s1; red2[i][wv] = s2; }
    }
    __syncthreads();
    if (tid < 4) {
      float s1 = red1[tid][0] + red1[tid][1] + red1[tid][2] + red1[tid][3];
      float s2 = red2[tid][0] + red2[tid][1] + red2[tid][2] + red2[tid][3];
      float mu = s1 * (1.f / 256.f);
      float var = fmaxf(s2 * (1.f / 256.f) - mu * mu, 0.f);
      muS[tid] = mu; rsS[tid] = rsqrtf(var + 1e-5f);
    }
    __syncthreads();
    float g = olng[tid], be = olnb[tid];
#pragma unroll
    for (int i = 0; i < 4; ++i) {
      float y = (hv[i] - muS[i]) * rsS[i] * g + be;
      c_out[(size_t)(m0 + i) * 256 + tid] = y;
      lstm_in[(size_t)(m0 + i) * 512 + tid] = y;
    }
  }
}

// ---- full multi-head attention over S<=9 rows (layer 1) ----
__global__ __launch_bounds__(128) void attn_k(const float* __restrict__ qkv,
                                              float* __restrict__ attnout, int S) {
  int bh = blockIdx.x;
  int b = bh >> 2, h = bh & 3;
  __shared__ float q[9][64], k[9][64], v[9][64], lg[9][12];
  int tid = threadIdx.x;
  for (int i = tid; i < S * 64; i += 128) {
    int s = i >> 6, d = i & 63;
    const float* base = qkv + (size_t)(s * BB + b) * 768 + h * 64 + d;
    q[s][d] = base[0]; k[s][d] = base[256]; v[s][d] = base[512];
  }
  __syncthreads();
  for (int p = tid; p < S * S; p += 128) {
    int s = p / S, t2 = p % S;
    float acc = 0.f;
    for (int d = 0; d < 64; ++d) acc += q[s][d] * k[t2][d];
    lg[s][t2] = acc * 0.125f;
  }
  __syncthreads();
  if (tid < S) {
    float mx = -1e30f;
    for (int t2 = 0; t2 < S; ++t2) mx = fmaxf(mx, lg[tid][t2]);
    float sum = 0.f;
    for (int t2 = 0; t2 < S; ++t2) { float e = expf(lg[tid][t2] - mx); lg[tid][t2] = e; sum += e; }
    float inv = 1.f / sum;
    for (int t2 = 0; t2 < S; ++t2) lg[tid][t2] *= inv;
  }
  __syncthreads();
  for (int i = tid; i < S * 64; i += 128) {
    int s = i >> 6, d = i & 63;
    float o = 0.f;
    for (int t2 = 0; t2 < S; ++t2) o += lg[s][t2] * v[t2][d];
    attnout[(size_t)(s * BB + b) * 256 + h * 64 + d] = o;
  }
}

// ---- last-row-only attention (layer 2) ----
__global__ __launch_bounds__(64) void attnl_k(const float* __restrict__ qkv,
                                              float* __restrict__ aout, int S) {
  int bh = blockIdx.x;
  int b = bh >> 2, h = bh & 3;
  int d = threadIdx.x;
  __shared__ float sc[9];
  float qd = qkv[(size_t)((S - 1) * BB + b) * 768 + h * 64 + d];
  for (int j = 0; j < S; ++j) {
    float p = qd * qkv[(size_t)(j * BB + b) * 768 + h * 64 + 256 + d];
#pragma unroll
    for (int o = 32; o > 0; o >>= 1) p += __shfl_down(p, o);
    if (d == 0) sc[j] = p * 0.125f;
  }
  __syncthreads();
  float mx = -1e30f;
  for (int j = 0; j < S; ++j) mx = fmaxf(mx, sc[j]);
  float pj[9], sum = 0.f;
  for (int j = 0; j < S; ++j) { pj[j] = expf(sc[j] - mx); sum += pj[j]; }
  float inv = 1.f / sum;
  float o = 0.f;
  for (int j = 0; j < S; ++j) o += pj[j] * inv * qkv[(size_t)(j * BB + b) * 768 + h * 64 + 512 + d];
  aout[(size_t)b * 256 + h * 64 + d] = o;
}

// ---- LSTM GEMM with fused pointwise epilogue (gate-interleaved Wc) ----
template <int LAST>
__global__ __launch_bounds__(256) void lstmg_k(
    const float* __restrict__ A, const float* __restrict__ W,
    const float* __restrict__ cbias, float* cx, float* li_l, float* li_next,
    const float* __restrict__ c_outp, float* c_fin, unsigned short* cfb,
    float* record) {
  __shared__ float As[2][16][36];
  __shared__ float Ws[2][16][68];
  const int tid = threadIdx.x, tx = tid & 15, ty = tid >> 4;
  const int n0 = blockIdx.x * 64;
  const int lar = tid >> 2, laq = (tid & 3) << 2;
  float4 a4 = make_float4(0.f, 0.f, 0.f, 0.f), w4;
  if (tid < 128) a4 = *(const float4*)(A + (size_t)lar * 512 + laq);
  w4 = *(const float4*)(W + (size_t)(n0 + lar) * 512 + laq);
  float acc[2][4] = {};
  int buf = 0;
  for (int kt = 0; kt < 32; ++kt) {
    if (tid < 128) {
      As[buf][laq + 0][lar] = a4.x; As[buf][laq + 1][lar] = a4.y;
      As[buf][laq + 2][lar] = a4.z; As[buf][laq + 3][lar] = a4.w;
    }
    Ws[buf][laq + 0][lar] = w4.x; Ws[buf][laq + 1][lar] = w4.y;
    Ws[buf][laq + 2][lar] = w4.z; Ws[buf][laq + 3][lar] = w4.w;
    __syncthreads();
    if (kt + 1 < 32) {
      const int k1 = (kt + 1) << 4;
      if (tid < 128) a4 = *(const float4*)(A + (size_t)lar * 512 + k1 + laq);
      w4 = *(const float4*)(W + (size_t)(n0 + lar) * 512 + k1 + laq);
    }
#pragma unroll
    for (int kk = 0; kk < 16; ++kk) {
      float2 av = *(const float2*)&As[buf][kk][ty << 1];
      float4 wv = *(const float4*)&Ws[buf][kk][tx << 2];
      acc[0][0] += av.x * wv.x; acc[0][1] += av.x * wv.y; acc[0][2] += av.x * wv.z; acc[0][3] += av.x * wv.w;
      acc[1][0] += av.y * wv.x; acc[1][1] += av.y * wv.y; acc[1][2] += av.y * wv.z; acc[1][3] += av.y * wv.w;
    }
    buf ^= 1;
  }
  const int d = (n0 >> 2) + tx;
#pragma unroll
  for (int i = 0; i < 2; ++i) {
    int b = ty * 2 + i;
    float gi = acc[i][0] + cbias[n0 + tx * 4 + 0];
    float gf = acc[i][1] + cbias[n0 + tx * 4 + 1];
    float gg = acc[i][2] + cbias[n0 + tx * 4 + 2];
    float go = acc[i][3] + cbias[n0 + tx * 4 + 3];
    float c = sigf(gf) * cx[b * 256 + d] + sigf(gi) * tanhf(gg);
    float hN = sigf(go) * tanhf(c);
    cx[b * 256 + d] = c;
    li_l[(size_t)b * 512 + 256 + d] = hN;
    if constexpr (LAST) {
      record[b * 256 + d] = hN;
      float cf = c_outp[b * 256 + d] + hN;
      c_fin[b * 256 + d] = cf;
      cfb[b * 256 + d] = f2bf(cf);
    } else {
      li_next[(size_t)b * 512 + d] = hN;
    }
  }
}

// ---- generic tiled GEMM (used for read/write params), TM=32 TN=64 ----
__global__ __launch_bounds__(256) void gemm_k(
    const float* __restrict__ A, const float* __restrict__ W,
    const float* __restrict__ bias, float* C, int M, int N, int K) {
  __shared__ float As[2][16][36];
  __shared__ float Ws[2][16][68];
  const int tid = threadIdx.x, tx = tid & 15, ty = tid >> 4;
  const int m0 = blockIdx.y * 32, n0 = blockIdx.x * 64;
  const int lar = tid >> 2, laq = (tid & 3) << 2;
  const int KT = K >> 4;
  float4 a4 = make_float4(0.f, 0.f, 0.f, 0.f), w4 = make_float4(0.f, 0.f, 0.f, 0.f);
  if (tid < 128) {
    const int m = m0 + lar;
    if (m < M) a4 = *(const float4*)(A + (size_t)m * K + laq);
  }
  { const int n = n0 + lar; if (n < N) w4 = *(const float4*)(W + (size_t)n * K + laq); }
  float acc[2][4] = {};
  int buf = 0;
  for (int kt = 0; kt < KT; ++kt) {
    if (tid < 128) {
      As[buf][laq + 0][lar] = a4.x; As[buf][laq + 1][lar] = a4.y;
      As[buf][laq + 2][lar] = a4.z; As[buf][laq + 3][lar] = a4.w;
    }
    Ws[buf][laq + 0][lar] = w4.x; Ws[buf][laq + 1][lar] = w4.y;
    Ws[buf][laq + 2][lar] = w4.z; Ws[buf][laq + 3][lar] = w4.w;
    __syncthreads();
    if (kt + 1 < KT) {
      const int k1 = (kt + 1) << 4;
      a4 = make_float4(0.f, 0.f, 0.f, 0.f); w4 = make_float4(0.f, 0.f, 0.f, 0.f);
      if (tid < 128) { const int m = m0 + lar; if (m < M) a4 = *(const float4*)(A + (size_t)m * K + k1 + laq); }
      { const int n = n0 + lar; if (n < N) w4 = *(const float4*)(W + (size_t)n * K + k1 + laq); }
    }
#pragma unroll
    for (int kk = 0; kk < 16; ++kk) {
      float2 av = *(const float2*)&As[buf][kk][ty << 1];
      float4 wv = *(const float4*)&Ws[buf][kk][tx << 2];
      acc[0][0] += av.x * wv.x; acc[0][1] += av.x * wv.y; acc[0][2] += av.x * wv.z; acc[0][3] += av.x * wv.w;
      acc[1][0] += av.y * wv.x; acc[1][1] += av.y * wv.y; acc[1][2] += av.y * wv.z; acc[1][3] += av.y * wv.w;
    }
    buf ^= 1;
  }
#pragma unroll
  for (int i = 0; i < 2; ++i) {
    const int m = m0 + ty * 2 + i;
    if (m >= M) continue;
#pragma unroll
    for (int j = 0; j < 4; ++j) {
      const int n = n0 + tx * 4 + j;
      if (n >= N) continue;
      C[(size_t)m * N + n] = acc[i][j] + bias[n];
    }
  }
}

// ---- head: logits = c_fin(bf16) @ head_W(bf16)^T + head_b via MFMA ----
__global__ __launch_bounds__(256) void head_k(const unsigned short* __restrict__ Wh,
                                              const unsigned short* __restrict__ Ah,
                                              const float* __restrict__ hb,
                                              float* __restrict__ out) {
  const int tid = threadIdx.x;
  const int w = tid >> 6, l = tid & 63;
  const int r = l & 15, q = l >> 4;
  const int n = blockIdx.x * 64 + w * 16 + r;
  const int nc = n < VV ? n : VV - 1;
  const short* Ap = (const short*)Ah;
  const short* Wp = (const short*)Wh + (size_t)nc * 256;
  short8 a0[8], a1[8], bf[8];
#pragma unroll
  for (int kt = 0; kt < 8; ++kt) {
    a0[kt] = *(const short8*)(Ap + r * 256 + kt * 32 + q * 8);
    a1[kt] = *(const short8*)(Ap + (16 + r) * 256 + kt * 32 + q * 8);
    bf[kt] = *(const short8*)(Wp + kt * 32 + q * 8);
  }
  f32x4 acc0 = {0.f, 0.f, 0.f, 0.f}, acc1 = {0.f, 0.f, 0.f, 0.f};
#pragma unroll
  for (int kt = 0; kt < 8; ++kt) {
    acc0 = __builtin_amdgcn_mfma_f32_16x16x32_bf16(a0[kt], bf[kt], acc0, 0, 0, 0);
    acc1 = __builtin_amdgcn_mfma_f32_16x16x32_bf16(a1[kt], bf[kt], acc1, 0, 0, 0);
  }
  if (n < VV) {
    float bb = hb[n];
#pragma unroll
    for (int e = 0; e < 4; ++e) {
      int m = q * 4 + e;
      out[(size_t)m * VV + n] = acc0[e] + bb;
      out[(size_t)(16 + m) * VV + n] = acc1[e] + bb;
    }
  }
}

// ---- pass A over bf16 memory: dots + row norms ----
__global__ __launch_bounds__(256) void passA_k(const unsigned short* __restrict__ mem,
                                               const float* __restrict__ rpwp,
                                               float* __restrict__ dr,
                                               float* __restrict__ dw,
                                               float* __restrict__ nrm) {
  __shared__ float kr[256], kw[256];
  int b = blockIdx.y, tid = threadIdx.x;
  kr[tid] = rpwp[(size_t)b * 1036 + tid];
  kw[tid] = rpwp[(size_t)b * 1036 + 262 + tid];
  __syncthreads();
  int w = tid >> 6, lane = tid & 63;
  float4 kr4 = *(float4*)&kr[lane * 4];
  float4 kw4 = *(float4*)&kw[lane * 4];
  int n0 = blockIdx.x * 16 + w * 4;
  for (int rr = 0; rr < 4; ++rr) {
    int n = n0 + rr;
    const unsigned short* row = mem + ((size_t)b * NN + n) * 256;
    uint2 p = *(const uint2*)(row + lane * 4);
    float m0 = bf2f(p.x & 0xffffu), m1 = bf2f(p.x >> 16);
    float m2 = bf2f(p.y & 0xffffu), m3 = bf2f(p.y >> 16);
    float pr = m0 * kr4.x + m1 * kr4.y + m2 * kr4.z + m3 * kr4.w;
    float pw = m0 * kw4.x + m1 * kw4.y + m2 * kw4.z + m3 * kw4.w;
    float pn = m0 * m0 + m1 * m1 + m2 * m2 + m3 * m3;
#pragma unroll
    for (int o = 32; o > 0; o >>= 1) {
      pr += __shfl_down(pr, o); pw += __shfl_down(pw, o); pn += __shfl_down(pn, o);
    }
    if (lane == 0) {
      dr[(size_t)b * NN + n] = pr;
      dw[(size_t)b * NN + n] = pw;
      nrm[(size_t)b * NN + n] = pn;
    }
  }
}

// ---- addressing ----
__global__ __launch_bounds__(256) void addr_k(const float* __restrict__ dr,
                                              const float* __restrict__ dw,
                                              const float* __restrict__ nrm,
                                              const float* __restrict__ rpwp,
                                              float* rw, float* ww,
                                              float* __restrict__ ea,
                                              float* __restrict__ rvec) {
  __shared__ float wg[4096];
  __shared__ float s8[8];
  int head = blockIdx.x & 1, b = blockIdx.x >> 1;
  int tid = threadIdx.x;
  const float* p = rpwp + (size_t)b * 1036 + (head ? 262 : 0);
  const float* dot = (head ? dw : dr) + (size_t)b * NN;
  const float* n2 = nrm + (size_t)b * NN;
  float* wout = (head ? ww : rw) + (size_t)b * NN;

  float kv = p[tid];
  float kn = sqrtf(blk_sum(kv * kv, s8)) + EPS_;
  float beta = p[256], gate = p[257], sh0 = p[258], sh1 = p[259], sh2 = p[260], gamma = p[261];
  float spb = softplusf_(beta);
  float g = sigf(gate);
  float mx3 = fmaxf(sh0, fmaxf(sh1, sh2));
  float e0 = expf(sh0 - mx3), e1 = expf(sh1 - mx3), e2 = expf(sh2 - mx3);
  float esum = e0 + e1 + e2;
  float s0 = e0 / esum, s1 = e1 / esum, s2 = e2 / esum;
  float gp = 1.f + softplusf_(gamma);

  float l[16];
  float lmax = -1e30f;
#pragma unroll
  for (int i = 0; i < 16; ++i) {
    int n = tid + i * 256;
    float cs = dot[n] / ((sqrtf(n2[n]) + EPS_) * kn);
    l[i] = spb * cs;
    lmax = fmaxf(lmax, l[i]);
  }
  float Mx = blk_max(lmax, s8);
  float es = 0.f;
#pragma unroll
  for (int i = 0; i < 16; ++i) { l[i] = expf(l[i] - Mx); es += l[i]; }
  float SS = blk_sum(es, s8);
  float inv = 1.f / SS;
#pragma unroll
  for (int i = 0; i < 16; ++i) {
    int n = tid + i * 256;
    wg[n] = g * l[i] * inv + (1.f - g) * wout[n];
  }
  __syncthreads();
  float wt[16];
  float wsum = 0.f;
#pragma unroll
  for (int i = 0; i < 16; ++i) {
    int n = tid + i * 256;
    float sh = s0 * wg[(n + 1) & 4095] + s1 * wg[n] + s2 * wg[(n + 4095) & 4095];
    wt[i] = powf(sh + EPS_, gp);
    wsum += wt[i];
  }
  float WS = blk_sum(wsum, s8) + EPS_;
  float winv = 1.f / WS;
#pragma unroll
  for (int i = 0; i < 16; ++i) wout[tid + i * 256] = wt[i] * winv;

  if (head) {
    ea[(size_t)b * 512 + tid] = sigf(p[262 + tid]);
    ea[(size_t)b * 512 + 256 + tid] = tanhf(p[518 + tid]);
  } else {
    rvec[(size_t)b * 256 + tid] = 0.f;
  }
}

// ---- pass B over bf16 memory: erase/add + fused r = rw . mem_new ----
template <int FIRST>
__global__ __launch_bounds__(256) void passB_k(unsigned short* mem, const float* __restrict__ ww,
                                               const float* __restrict__ rw,
                                               const float* __restrict__ ea,
                                               float* __restrict__ rvec) {
  __shared__ float eS[256], aS[256];
  __shared__ float rred[4][256];
  int b = blockIdx.y, tid = threadIdx.x;
  eS[tid] = ea[(size_t)b * 512 + tid];
  aS[tid] = ea[(size_t)b * 512 + 256 + tid];
  __syncthreads();
  int w = tid >> 6, lane = tid & 63;
  float4 e4 = *(float4*)&eS[lane * 4];
  float4 a4 = *(float4*)&aS[lane * 4];
  float4 racc = make_float4(0.f, 0.f, 0.f, 0.f);
  int n0 = blockIdx.x * 128 + w * 32;
  for (int rr = 0; rr < 32; ++rr) {
    int n = n0 + rr;
    float wt = ww[(size_t)b * NN + n];
    float rwv = rw[(size_t)b * NN + n];
    unsigned short* row = mem + ((size_t)b * NN + n) * 256;
    float m0, m1, m2, m3;
    if (FIRST) {
      m0 = wt * a4.x; m1 = wt * a4.y; m2 = wt * a4.z; m3 = wt * a4.w;
    } else {
      uint2 p = *(const uint2*)(row + lane * 4);
      m0 = bf2f(p.x & 0xffffu) * (1.f - wt * e4.x) + wt * a4.x;
      m1 = bf2f(p.x >> 16) * (1.f - wt * e4.y) + wt * a4.y;
      m2 = bf2f(p.y & 0xffffu) * (1.f - wt * e4.z) + wt * a4.z;
      m3 = bf2f(p.y >> 16) * (1.f - wt * e4.w) + wt * a4.w;
    }
    uint2 pk;
    pk.x = (unsigned)f2bf(m0) | ((unsigned)f2bf(m1) << 16);
    pk.y = (unsigned)f2bf(m2) | ((unsigned)f2bf(m3) << 16);
    *(uint2*)(row + lane * 4) = pk;
    racc.x += rwv * m0; racc.y += rwv * m1; racc.z += rwv * m2; racc.w += rwv * m3;
  }
  rred[w][lane * 4 + 0] = racc.x;
  rred[w][lane * 4 + 1] = racc.y;
  rred[w][lane * 4 + 2] = racc.z;
  rred[w][lane * 4 + 3] = racc.w;
  __syncthreads();
  float s = rred[0][tid] + rred[1][tid] + rred[2][tid] + rred[3][tid];
  atomicAdd(rvec + (size_t)b * 256 + tid, s);
}

extern "C" void kernel_launch(void* const* d_in, const int* in_sizes, int n_in,
                              void* d_out, int out_size, void* d_ws, size_t ws_size,
                              hipStream_t stream) {
  const int* tokens = (const int*)d_in[0];
  const float* emb_W = (const float*)d_in[1];
  const float* read_gate_W = (const float*)d_in[2];
  const float* read_gate_b = (const float*)d_in[3];
  const float* film_W = (const float*)d_in[4];
  const float* film_b = (const float*)d_in[5];
  const float* t_Wqkv = (const float*)d_in[6];
  const float* t_bqkv = (const float*)d_in[7];
  const float* t_Wo = (const float*)d_in[8];
  const float* t_bo = (const float*)d_in[9];
  const float* t_ln1_g = (const float*)d_in[10];
  const float* t_ln1_b = (const float*)d_in[11];
  const float* t_ln2_g = (const float*)d_in[12];
  const float* t_ln2_b = (const float*)d_in[13];
  const float* t_W1 = (const float*)d_in[14];
  const float* t_b1 = (const float*)d_in[15];
  const float* t_W2 = (const float*)d_in[16];
  const float* t_b2 = (const float*)d_in[17];
  const float* out_ln_g = (const float*)d_in[18];
  const float* out_ln_b = (const float*)d_in[19];
  const float* lstm_Wih = (const float*)d_in[20];
  const float* lstm_Whh = (const float*)d_in[21];
  const float* lstm_bih = (const float*)d_in[22];
  const float* lstm_bhh = (const float*)d_in[23];
  const float* head_W = (const float*)d_in[24];
  const float* head_b = (const float*)d_in[25];
  const float* read_W = (const float*)d_in[26];
  const float* read_b = (const float*)d_in[27];
  const float* write_W = (const float*)d_in[28];
  const float* write_b = (const float*)d_in[29];
  float* out = (float*)d_out;

  float* ws = (float*)d_ws;
  size_t off = 0;
  // ---- zero-initialized region ----
  float* read_w = ws + off; off += (size_t)BB * NN;
  float* write_w = ws + off; off += (size_t)BB * NN;
  float* record = ws + off; off += BB * DD;
  float* cx = ws + off; off += 2 * BB * DD;
  float* lstm_in = ws + off; off += 2 * BB * 512;
  float* r_vec = ws + off; off += BB * DD;
  float* dot_r = ws + off; off += (size_t)BB * NN;
  float* dot_w = ws + off; off += (size_t)BB * NN;
  float* norm2 = ws + off; off += (size_t)BB * NN;
  size_t zero_floats = off;
  // ---- not zeroed ----
  unsigned short* memory = (unsigned short*)(ws + off); off += (size_t)BB * NN * DD / 2;
  float* hpe = ws + off; off += 9 * BB * DD;
  float* h = ws + off; off += 9 * BB * DD;
  float* qkv = ws + off; off += 9 * BB * 3 * DD;
  float* attnout = ws + off; off += 9 * BB * DD;
  float* attnl = ws + off; off += BB * DD;
  float* x2 = ws + off; off += 9 * BB * DD;
  float* mid = ws + off; off += 9 * BB * 4 * DD;
  float* c_out = ws + off; off += BB * DD;
  float* c_fin = ws + off; off += BB * DD;
  float* rpwp = ws + off; off += BB * 1036;
  float* ea = ws + off; off += BB * 2 * DD;
  float* Wc2 = ws + off; off += 2 * 1024 * 512;
  float* cb2 = ws + off; off += 2 * 1024;
  float* Wrw = ws + off; off += 1036 * 256;
  float* brw = ws + off; off += 1040;
  float* WTq = ws + off; off += 2 * 256 * 768;
  float* WTo = ws + off; off += 2 * 256 * 256;
  float* WT1 = ws + off; off += 2 * 256 * 1024;
  float* WT2 = ws + off; off += 2 * 1024 * 256;
  float* FRT = ws + off; off += 256 * 768;
  unsigned short* Wh = (unsigned short*)(ws + off); off += (size_t)VV * 256 / 2;
  unsigned short* cfb = (unsigned short*)(ws + off); off += BB * DD / 2;
  if (ws_size < off * sizeof(float)) return;

  (void)hipMemsetAsync(ws, 0, zero_floats * sizeof(float), stream);
  init_k<<<32, 256, 0, stream>>>(read_w, write_w, hpe);
  cvtw_k<<<(VV * 256 / 4 + 255) / 256, 256, 0, stream>>>(head_W, Wh, VV * 256 / 4);
  catlstm_k<<<4096, 256, 0, stream>>>(lstm_Wih, lstm_Whh, lstm_bih, lstm_bhh, Wc2, cb2);
  catrw_k<<<1036, 256, 0, stream>>>(read_W, read_b, write_W, write_b, Wrw, brw);
  tr_k<<<dim3(8, 16), 256, 0, stream>>>(film_W, FRT, 512, 256, 768, 0);
  tr_k<<<dim3(8, 8), 256, 0, stream>>>(read_gate_W, FRT, 256, 256, 768, 512);
  for (int l = 0; l < 2; ++l) {
    tr_k<<<dim3(8, 24), 256, 0, stream>>>(t_Wqkv + (size_t)l * 768 * 256, WTq + (size_t)l * 256 * 768, 768, 256, 768, 0);
    tr_k<<<dim3(8, 8), 256, 0, stream>>>(t_Wo + (size_t)l * 256 * 256, WTo + (size_t)l * 256 * 256, 256, 256, 256, 0);
    tr_k<<<dim3(8, 32), 256, 0, stream>>>(t_W1 + (size_t)l * 1024 * 256, WT1 + (size_t)l * 256 * 1024, 1024, 256, 1024, 0);
    tr_k<<<dim3(32, 8), 256, 0, stream>>>(t_W2 + (size_t)l * 256 * 1024, WT2 + (size_t)l * 1024 * 256, 256, 1024, 256, 0);
  }

  for (int t = 0; t < TT; ++t) {
    const int S = t + 2;
    const int M = S * BB;
    float* hL = h + (size_t)(S - 1) * BB * DD;  // last-row block of h

    xin2_k<<<8, 256, 0, stream>>>(tokens, emb_W, FRT, film_b, read_gate_b, record, r_vec, hpe, t);

    // ---- layer 1 (all rows) ----
    qkv_k<<<dim3(3, M / 8), 256, 0, stream>>>(hpe, WTq, t_bqkv, t_ln1_g, t_ln1_b, qkv);
    attn_k<<<BB * 4, 128, 0, stream>>>(qkv, attnout, S);
    proj_k<<<M / 8, 256, 0, stream>>>(attnout, WTo, t_bo, hpe, h, t_ln2_g, t_ln2_b, x2);
    ffn1_k<<<dim3(4, M / 8), 256, 0, stream>>>(x2, WT1, t_b1, mid);
    ffn2_k<0><<<M / 4, 256, 0, stream>>>(mid, WT2, t_b2, h, h, nullptr, nullptr, nullptr, nullptr);

    // ---- layer 2 (k/v all rows; proj/ffn last row only) ----
    qkv_k<<<dim3(3, M / 8), 256, 0, stream>>>(h, WTq + 256 * 768, t_bqkv + 768,
                                              t_ln1_g + 256, t_ln1_b + 256, qkv);
    attnl_k<<<BB * 4, 64, 0, stream>>>(qkv, attnl, S);
    proj_k<<<4, 256, 0, stream>>>(attnl, WTo + 256 * 256, t_bo + 256, hL, hL,
                                  t_ln2_g + 256, t_ln2_b + 256, x2);
    ffn1_k<<<dim3(4, 4), 256, 0, stream>>>(x2, WT1 + 256 * 1024, t_b1 + 1024, mid);
    ffn2_k<1><<<8, 256, 0, stream>>>(mid, WT2 + 1024 * 256, t_b2 + 256, hL, hL,
                                     out_ln_g, out_ln_b, c_out, lstm_in);

    // ---- LSTM (2 layers, fused epilogue) ----
    lstmg_k<0><<<16, 256, 0, stream>>>(lstm_in, Wc2, cb2, cx, lstm_in,
                                       lstm_in + (size_t)BB * 512, nullptr, nullptr, nullptr, nullptr);
    lstmg_k<1><<<16, 256, 0, stream>>>(lstm_in + (size_t)BB * 512, Wc2 + (size_t)1024 * 512,
                                       cb2 + 1024, cx + BB * DD, lstm_in + (size_t)BB * 512,
                                       nullptr, c_out, c_fin, cfb, record);

    head_k<<<(VV + 63) / 64, 256, 0, stream>>>(Wh, cfb, head_b, out + (size_t)t * BB * VV);

    if (t < TT - 1) {
      gemm_k<<<dim3(17, 1), 256, 0, stream>>>(c_fin, Wrw, brw, rpwp, BB, 1036, 256);
      if (t > 0)
        passA_k<<<dim3(NN / 16, BB), 256, 0, stream>>>(memory, rpwp, dot_r, dot_w, norm2);
      addr_k<<<2 * BB, 256, 0, stream>>>(dot_r, dot_w, norm2, rpwp, read_w, write_w, ea, r_vec);
      if (t == 0)
        passB_k<1><<<dim3(NN / 128, BB), 256, 0, stream>>>(memory, write_w, read_w, ea, r_vec);
      else
        passB_k<0><<<dim3(NN / 128, BB), 256, 0, stream>>>(memory, write_w, read_w, ea, r_vec);
    }
  }
}

// Round 5
// 1679.087 us; speedup vs baseline: 2.4507x; 1.7005x over previous
//
#include <hip/hip_runtime.h>
#include <math.h>

#define TT 8
#define BB 32
#define VV 50257
#define DD 256
#define NN 4096
#define EPS_ 1e-12f

typedef __attribute__((ext_vector_type(8))) short short8;
typedef __attribute__((ext_vector_type(4))) float f32x4;

__device__ __forceinline__ float sigf(float x) { return 1.f / (1.f + expf(-x)); }
__device__ __forceinline__ float softplusf_(float x) { return fmaxf(x, 0.f) + log1pf(expf(-fabsf(x))); }
__device__ __forceinline__ unsigned f2bf(float f) {
  union { float f; unsigned u; } c; c.f = f;
  return (c.u + 0x7FFFu + ((c.u >> 16) & 1u)) >> 16;
}
__device__ __forceinline__ float bf2f(unsigned u16) {
  union { unsigned u; float f; } c; c.u = u16 << 16; return c.f;
}

// ---- block reductions (256-thread blocks only) ----
__device__ __forceinline__ float blk_sum(float v, float* s) {
#pragma unroll
  for (int o = 32; o > 0; o >>= 1) v += __shfl_down(v, o);
  __syncthreads();
  if ((threadIdx.x & 63) == 0) s[threadIdx.x >> 6] = v;
  __syncthreads();
  return s[0] + s[1] + s[2] + s[3];
}
__device__ __forceinline__ float blk_max(float v, float* s) {
#pragma unroll
  for (int o = 32; o > 0; o >>= 1) v = fmaxf(v, __shfl_down(v, o));
  __syncthreads();
  if ((threadIdx.x & 63) == 0) s[threadIdx.x >> 6] = v;
  __syncthreads();
  return fmaxf(fmaxf(s[0], s[1]), fmaxf(s[2], s[3]));
}

// ---- one-time init: one-hot weights + hpe row 0 (zeros + pe[0]) ----
__global__ void init_k(float* rw, float* ww, float* hpe) {
  int i = blockIdx.x * 256 + threadIdx.x;
  if (i < BB) { rw[(size_t)i * NN] = 1.f; ww[(size_t)i * NN] = 1.f; }
  if (i < BB * DD) hpe[i] = (i & 1) ? 1.f : 0.f;
}

// ---- f32 -> bf16 elementwise (4/thread) ----
__global__ void cvtw_k(const float* __restrict__ W, unsigned short* __restrict__ Wh, int n4) {
  int i = blockIdx.x * 256 + threadIdx.x;
  if (i >= n4) return;
  float4 v = *(const float4*)(W + (size_t)i * 4);
  uint2 p;
  p.x = f2bf(v.x) | (f2bf(v.y) << 16);
  p.y = f2bf(v.z) | (f2bf(v.w) << 16);
  *(uint2*)(Wh + (size_t)i * 4) = p;
}

// ---- combined LSTM weights bf16, gate-interleaved rows n' = d*4+gate, K=512 ----
__global__ void catlstm_k(const float* __restrict__ Wih, const float* __restrict__ Whh,
                          const float* __restrict__ bih, const float* __restrict__ bhh,
                          unsigned short* __restrict__ Wc, float* __restrict__ cb) {
  int i = blockIdx.x * 256 + threadIdx.x;
  if (i >= 2 * 1024 * 512) return;
  int k = i & 511, np = (i >> 9) & 1023, l = i >> 19;
  int d = np >> 2, gate = np & 3;
  int src = gate * 256 + d;
  float v = (k < 256) ? Wih[((size_t)l * 1024 + src) * 256 + k]
                      : Whh[((size_t)l * 1024 + src) * 256 + (k - 256)];
  Wc[i] = (unsigned short)f2bf(v);
  if (k == 0) cb[l * 1024 + np] = bih[l * 1024 + src] + bhh[l * 1024 + src];
}

// ---- combined read/write param weights bf16 (1036 x 256, padded to 1088) + f32 bias ----
__global__ void catrw_k(const float* __restrict__ rW, const float* __restrict__ rb,
                        const float* __restrict__ wW, const float* __restrict__ wb,
                        unsigned short* __restrict__ Wrw, float* __restrict__ brw) {
  int i = blockIdx.x * 256 + threadIdx.x;
  if (i >= 1036 * 256) return;
  int k = i & 255, n = i >> 8;
  float v = (n < 262) ? rW[(size_t)n * 256 + k] : wW[(size_t)(n - 262) * 256 + k];
  Wrw[i] = (unsigned short)f2bf(v);
  if (k == 0) brw[n] = (n < 262) ? rb[n] : wb[n - 262];
}

// ---- bias concat film_b|rgb (768) ----
__global__ void brc_k(const float* __restrict__ fb, const float* __restrict__ rb, float* __restrict__ brc) {
  int i = blockIdx.x * 256 + threadIdx.x;
  if (i < 512) brc[i] = fb[i];
  else if (i < 768) brc[i] = rb[i - 512];
}

// ---- LN1(layer0) of ctx row 0 -> q1b ----
__global__ __launch_bounds__(256) void ln0_k(const float* __restrict__ hpe,
                                             const float* __restrict__ g1, const float* __restrict__ b1,
                                             unsigned short* __restrict__ q1b) {
  __shared__ float s8[8];
  int b = blockIdx.x, d = threadIdx.x;
  float v = hpe[(size_t)b * 256 + d];
  float mu = blk_sum(v, s8) * (1.f / 256.f);
  float dd = v - mu;
  float var = blk_sum(dd * dd, s8) * (1.f / 256.f);
  float rs = rsqrtf(var + 1e-5f);
  q1b[(size_t)b * 256 + d] = (unsigned short)f2bf(dd * rs * g1[d] + b1[d]);
}

// ============ MFMA GEMM core A: 32m x 64n tile, K=256, 4 waves ============
// A [M][256] bf16, W [Nrows][256] bf16, out row-major ldc. EPI 0: f32; 1: relu->bf16.
template <int EPI>
__global__ __launch_bounds__(256) void gA_k(const unsigned short* __restrict__ A,
                                            const unsigned short* __restrict__ W,
                                            const float* __restrict__ bias,
                                            float* __restrict__ Cf,
                                            unsigned short* __restrict__ Cb,
                                            int ldc, int Nlim) {
  const int tid = threadIdx.x, w = tid >> 6, l = tid & 63, r = l & 15, q = l >> 4;
  const int m0 = blockIdx.y * 32;
  const int n = blockIdx.x * 64 + w * 16 + r;
  const unsigned short* Ap = A + (size_t)m0 * 256;
  const unsigned short* Wp = W + (size_t)n * 256;
  f32x4 acc0 = {0.f, 0.f, 0.f, 0.f}, acc1 = {0.f, 0.f, 0.f, 0.f};
#pragma unroll
  for (int kt = 0; kt < 8; ++kt) {
    short8 a0 = *(const short8*)(Ap + r * 256 + kt * 32 + q * 8);
    short8 a1 = *(const short8*)(Ap + (16 + r) * 256 + kt * 32 + q * 8);
    short8 bf = *(const short8*)(Wp + kt * 32 + q * 8);
    acc0 = __builtin_amdgcn_mfma_f32_16x16x32_bf16(a0, bf, acc0, 0, 0, 0);
    acc1 = __builtin_amdgcn_mfma_f32_16x16x32_bf16(a1, bf, acc1, 0, 0, 0);
  }
  if (n >= Nlim) return;
  float bb = bias[n];
#pragma unroll
  for (int e = 0; e < 4; ++e) {
    int m1 = m0 + q * 4 + e, m2 = m1 + 16;
    float v1 = acc0[e] + bb, v2 = acc1[e] + bb;
    if constexpr (EPI == 0) {
      Cf[(size_t)m1 * ldc + n] = v1;
      Cf[(size_t)m2 * ldc + n] = v2;
    } else {
      Cb[(size_t)m1 * ldc + n] = (unsigned short)f2bf(fmaxf(v1, 0.f));
      Cb[(size_t)m2 * ldc + n] = (unsigned short)f2bf(fmaxf(v2, 0.f));
    }
  }
}

// ======= MFMA GEMM core B: 32m x 256n tile + residual + row-LN epilogue =======
// OLN=0: Hout=f32(acc+bias+resid), Xb=bf16 LN rows (stride xstride)
// OLN=1: additionally c_out = f32 LN rows (out_ln); Xb = lstm x-part (stride 512)
template <int K, int OLN>
__global__ __launch_bounds__(256) void gB_k(const unsigned short* __restrict__ A,
                                            const unsigned short* __restrict__ W,
                                            const float* __restrict__ bias,
                                            const float* __restrict__ resid,
                                            float* __restrict__ Hout,
                                            const float* __restrict__ lng,
                                            const float* __restrict__ lnb,
                                            unsigned short* __restrict__ Xb, int xstride,
                                            float* __restrict__ c_out) {
  __shared__ float hv[32][260];
  const int tid = threadIdx.x, w = tid >> 6, l = tid & 63, r = l & 15, q = l >> 4;
  const int m0 = blockIdx.x * 32;
  const unsigned short* Ap = A + (size_t)m0 * K;
  const unsigned short* Wp0 = W + (size_t)(w * 64 + 0 + r) * K;
  const unsigned short* Wp1 = W + (size_t)(w * 64 + 16 + r) * K;
  const unsigned short* Wp2 = W + (size_t)(w * 64 + 32 + r) * K;
  const unsigned short* Wp3 = W + (size_t)(w * 64 + 48 + r) * K;
  f32x4 acc0[4], acc1[4];
#pragma unroll
  for (int j = 0; j < 4; ++j) { acc0[j] = {0.f, 0.f, 0.f, 0.f}; acc1[j] = {0.f, 0.f, 0.f, 0.f}; }
#pragma unroll 4
  for (int kt = 0; kt < K / 32; ++kt) {
    short8 a0 = *(const short8*)(Ap + (size_t)r * K + kt * 32 + q * 8);
    short8 a1 = *(const short8*)(Ap + (size_t)(16 + r) * K + kt * 32 + q * 8);
    short8 b0 = *(const short8*)(Wp0 + kt * 32 + q * 8);
    short8 b1 = *(const short8*)(Wp1 + kt * 32 + q * 8);
    short8 b2 = *(const short8*)(Wp2 + kt * 32 + q * 8);
    short8 b3 = *(const short8*)(Wp3 + kt * 32 + q * 8);
    acc0[0] = __builtin_amdgcn_mfma_f32_16x16x32_bf16(a0, b0, acc0[0], 0, 0, 0);
    acc1[0] = __builtin_amdgcn_mfma_f32_16x16x32_bf16(a1, b0, acc1[0], 0, 0, 0);
    acc0[1] = __builtin_amdgcn_mfma_f32_16x16x32_bf16(a0, b1, acc0[1], 0, 0, 0);
    acc1[1] = __builtin_amdgcn_mfma_f32_16x16x32_bf16(a1, b1, acc1[1], 0, 0, 0);
    acc0[2] = __builtin_amdgcn_mfma_f32_16x16x32_bf16(a0, b2, acc0[2], 0, 0, 0);
    acc1[2] = __builtin_amdgcn_mfma_f32_16x16x32_bf16(a1, b2, acc1[2], 0, 0, 0);
    acc0[3] = __builtin_amdgcn_mfma_f32_16x16x32_bf16(a0, b3, acc0[3], 0, 0, 0);
    acc1[3] = __builtin_amdgcn_mfma_f32_16x16x32_bf16(a1, b3, acc1[3], 0, 0, 0);
  }
#pragma unroll
  for (int j = 0; j < 4; ++j) {
    int n = w * 64 + j * 16 + r;
    float bb = bias[n];
#pragma unroll
    for (int e = 0; e < 4; ++e) {
      int m1 = q * 4 + e, m2 = m1 + 16;
      float v1 = acc0[j][e] + bb + resid[(size_t)(m0 + m1) * 256 + n];
      float v2 = acc1[j][e] + bb + resid[(size_t)(m0 + m2) * 256 + n];
      Hout[(size_t)(m0 + m1) * 256 + n] = v1;
      Hout[(size_t)(m0 + m2) * 256 + n] = v2;
      hv[m1][n] = v1;
      hv[m2][n] = v2;
    }
  }
  __syncthreads();
  const float4 g4 = *(const float4*)(lng + l * 4);
  const float4 be4 = *(const float4*)(lnb + l * 4);
#pragma unroll
  for (int i = 0; i < 8; ++i) {
    int row = w * 8 + i;
    float4 v = *(const float4*)&hv[row][l * 4];
    float s1 = v.x + v.y + v.z + v.w;
    float s2 = v.x * v.x + v.y * v.y + v.z * v.z + v.w * v.w;
#pragma unroll
    for (int o = 32; o > 0; o >>= 1) { s1 += __shfl_xor(s1, o); s2 += __shfl_xor(s2, o); }
    float mu = s1 * (1.f / 256.f);
    float var = fmaxf(s2 * (1.f / 256.f) - mu * mu, 0.f);
    float rs = rsqrtf(var + 1e-5f);
    float y0 = (v.x - mu) * rs * g4.x + be4.x;
    float y1 = (v.y - mu) * rs * g4.y + be4.y;
    float y2 = (v.z - mu) * rs * g4.z + be4.z;
    float y3 = (v.w - mu) * rs * g4.w + be4.w;
    uint2 pk;
    pk.x = f2bf(y0) | (f2bf(y1) << 16);
    pk.y = f2bf(y2) | (f2bf(y3) << 16);
    *(uint2*)(Xb + (size_t)(m0 + row) * xstride + l * 4) = pk;
    if constexpr (OLN) {
      float4 cv = make_float4(y0, y1, y2, y3);
      *(float4*)(c_out + (size_t)(m0 + row) * 256 + l * 4) = cv;
    }
  }
}

// ======= LSTM MFMA GEMM (K=512, gate-interleaved N=1024) + pointwise epilogue =======
template <int LAST>
__global__ __launch_bounds__(256) void gL_k(const unsigned short* __restrict__ A,
                                            const unsigned short* __restrict__ W,
                                            const float* __restrict__ cbias,
                                            float* __restrict__ cx,
                                            unsigned short* __restrict__ li_own,
                                            unsigned short* __restrict__ li_next,
                                            const float* __restrict__ c_outp,
                                            unsigned short* __restrict__ cfinb,
                                            unsigned short* __restrict__ record_b) {
  __shared__ float g[32][68];
  const int tid = threadIdx.x, w = tid >> 6, l = tid & 63, r = l & 15, q = l >> 4;
  const int n = blockIdx.x * 64 + w * 16 + r;
  const unsigned short* Wp = W + (size_t)n * 512;
  f32x4 acc0 = {0.f, 0.f, 0.f, 0.f}, acc1 = {0.f, 0.f, 0.f, 0.f};
#pragma unroll 4
  for (int kt = 0; kt < 16; ++kt) {
    short8 a0 = *(const short8*)(A + (size_t)r * 512 + kt * 32 + q * 8);
    short8 a1 = *(const short8*)(A + (size_t)(16 + r) * 512 + kt * 32 + q * 8);
    short8 bf = *(const short8*)(Wp + kt * 32 + q * 8);
    acc0 = __builtin_amdgcn_mfma_f32_16x16x32_bf16(a0, bf, acc0, 0, 0, 0);
    acc1 = __builtin_amdgcn_mfma_f32_16x16x32_bf16(a1, bf, acc1, 0, 0, 0);
  }
  float bb = cbias[n];
  int nb = w * 16 + r;
#pragma unroll
  for (int e = 0; e < 4; ++e) {
    g[q * 4 + e][nb] = acc0[e] + bb;
    g[16 + q * 4 + e][nb] = acc1[e] + bb;
  }
  __syncthreads();
#pragma unroll
  for (int h2 = 0; h2 < 2; ++h2) {
    int u = tid + 256 * h2;
    int b = u >> 4, dd = u & 15;
    int dg = blockIdx.x * 16 + dd;
    float gi = g[b][dd * 4 + 0], gf = g[b][dd * 4 + 1];
    float gg = g[b][dd * 4 + 2], go = g[b][dd * 4 + 3];
    float c = sigf(gf) * cx[b * 256 + dg] + sigf(gi) * tanhf(gg);
    float hN = sigf(go) * tanhf(c);
    cx[b * 256 + dg] = c;
    li_own[(size_t)b * 512 + 256 + dg] = (unsigned short)f2bf(hN);
    if constexpr (LAST) {
      record_b[b * 256 + dg] = (unsigned short)f2bf(hN);
      cfinb[b * 256 + dg] = (unsigned short)f2bf(c_outp[b * 256 + dg] + hN);
    } else {
      li_next[(size_t)b * 512 + dg] = (unsigned short)f2bf(hN);
    }
  }
}

// ---- xin pointwise: FiLM nonlin + emb + gated read + PE -> hpe row; LN1 -> q1b ----
__global__ __launch_bounds__(256) void xinpw_k(const int* __restrict__ tokens,
                                               const float* __restrict__ embW,
                                               const float* __restrict__ fp,
                                               const float* __restrict__ rvec,
                                               const float* __restrict__ g1, const float* __restrict__ b1,
                                               float* __restrict__ hpe,
                                               unsigned short* __restrict__ q1b, int t) {
  __shared__ float s8[8];
  int b = blockIdx.x, d = threadIdx.x;
  float gam = 1.f + tanhf(fp[(size_t)b * 768 + d]);
  float bet = fp[(size_t)b * 768 + 256 + d];
  float rg = sigf(fp[(size_t)b * 768 + 512 + d]);
  int tok = tokens[t * BB + b];
  float emb = embW[(size_t)tok * 256 + d];
  float ang = (float)(t + 1) * expf(-logf(10000.f) * (float)(d & ~1) / 256.f);
  float pe = (d & 1) ? cosf(ang) : sinf(ang);
  float x = gam * emb + bet + rg * rvec[b * 256 + d] + pe;
  hpe[((size_t)(t + 1) * BB + b) * 256 + d] = x;
  float mu = blk_sum(x, s8) * (1.f / 256.f);
  float dd = x - mu;
  float var = blk_sum(dd * dd, s8) * (1.f / 256.f);
  float rs = rsqrtf(var + 1e-5f);
  q1b[((size_t)(t + 1) * BB + b) * 256 + d] = (unsigned short)f2bf(dd * rs * g1[d] + b1[d]);
}

// ---- full multi-head attention over S<=9 rows (layer 1), bf16 out ----
__global__ __launch_bounds__(128) void attn_k(const float* __restrict__ qkv,
                                              unsigned short* __restrict__ ao, int S) {
  int bh = blockIdx.x;
  int b = bh >> 2, h = bh & 3;
  __shared__ float q[9][64], k[9][64], v[9][64], lg[9][12];
  int tid = threadIdx.x;
  for (int i = tid; i < S * 64; i += 128) {
    int s = i >> 6, d = i & 63;
    const float* base = qkv + (size_t)(s * BB + b) * 768 + h * 64 + d;
    q[s][d] = base[0]; k[s][d] = base[256]; v[s][d] = base[512];
  }
  __syncthreads();
  for (int p = tid; p < S * S; p += 128) {
    int s = p / S, t2 = p % S;
    float acc = 0.f;
    for (int d = 0; d < 64; ++d) acc += q[s][d] * k[t2][d];
    lg[s][t2] = acc * 0.125f;
  }
  __syncthreads();
  if (tid < S) {
    float mx = -1e30f;
    for (int t2 = 0; t2 < S; ++t2) mx = fmaxf(mx, lg[tid][t2]);
    float sum = 0.f;
    for (int t2 = 0; t2 < S; ++t2) { float e = expf(lg[tid][t2] - mx); lg[tid][t2] = e; sum += e; }
    float inv = 1.f / sum;
    for (int t2 = 0; t2 < S; ++t2) lg[tid][t2] *= inv;
  }
  __syncthreads();
  for (int i = tid; i < S * 64; i += 128) {
    int s = i >> 6, d = i & 63;
    float o = 0.f;
    for (int t2 = 0; t2 < S; ++t2) o += lg[s][t2] * v[t2][d];
    ao[(size_t)(s * BB + b) * 256 + h * 64 + d] = (unsigned short)f2bf(o);
  }
}

// ---- last-row-only attention (layer 2), bf16 out ----
__global__ __launch_bounds__(64) void attnl_k(const float* __restrict__ qkv,
                                              unsigned short* __restrict__ ao, int S) {
  int bh = blockIdx.x;
  int b = bh >> 2, h = bh & 3;
  int d = threadIdx.x;
  __shared__ float sc[9];
  float qd = qkv[(size_t)((S - 1) * BB + b) * 768 + h * 64 + d];
  for (int j = 0; j < S; ++j) {
    float p = qd * qkv[(size_t)(j * BB + b) * 768 + h * 64 + 256 + d];
#pragma unroll
    for (int o = 32; o > 0; o >>= 1) p += __shfl_down(p, o);
    if (d == 0) sc[j] = p * 0.125f;
  }
  __syncthreads();
  float mx = -1e30f;
  for (int j = 0; j < S; ++j) mx = fmaxf(mx, sc[j]);
  float pj[9], sum = 0.f;
  for (int j = 0; j < S; ++j) { pj[j] = expf(sc[j] - mx); sum += pj[j]; }
  float inv = 1.f / sum;
  float o = 0.f;
  for (int j = 0; j < S; ++j) o += pj[j] * inv * qkv[(size_t)(j * BB + b) * 768 + h * 64 + 512 + d];
  ao[(size_t)b * 256 + h * 64 + d] = (unsigned short)f2bf(o);
}

// ---- head: logits = c_fin(bf16) @ head_W(bf16)^T + head_b via MFMA ----
__global__ __launch_bounds__(256) void head_k(const unsigned short* __restrict__ Wh,
                                              const unsigned short* __restrict__ Ah,
                                              const float* __restrict__ hb,
                                              float* __restrict__ out) {
  const int tid = threadIdx.x;
  const int w = tid >> 6, l = tid & 63;
  const int r = l & 15, q = l >> 4;
  const int n = blockIdx.x * 64 + w * 16 + r;
  const int nc = n < VV ? n : VV - 1;
  const short* Ap = (const short*)Ah;
  const short* Wp = (const short*)Wh + (size_t)nc * 256;
  short8 a0[8], a1[8], bf[8];
#pragma unroll
  for (int kt = 0; kt < 8; ++kt) {
    a0[kt] = *(const short8*)(Ap + r * 256 + kt * 32 + q * 8);
    a1[kt] = *(const short8*)(Ap + (16 + r) * 256 + kt * 32 + q * 8);
    bf[kt] = *(const short8*)(Wp + kt * 32 + q * 8);
  }
  f32x4 acc0 = {0.f, 0.f, 0.f, 0.f}, acc1 = {0.f, 0.f, 0.f, 0.f};
#pragma unroll
  for (int kt = 0; kt < 8; ++kt) {
    acc0 = __builtin_amdgcn_mfma_f32_16x16x32_bf16(a0[kt], bf[kt], acc0, 0, 0, 0);
    acc1 = __builtin_amdgcn_mfma_f32_16x16x32_bf16(a1[kt], bf[kt], acc1, 0, 0, 0);
  }
  if (n < VV) {
    float bb = hb[n];
#pragma unroll
    for (int e = 0; e < 4; ++e) {
      int m = q * 4 + e;
      out[(size_t)m * VV + n] = acc0[e] + bb;
      out[(size_t)(16 + m) * VV + n] = acc1[e] + bb;
    }
  }
}

// ---- pass A over bf16 memory: dots + row norms ----
__global__ __launch_bounds__(256) void passA_k(const unsigned short* __restrict__ mem,
                                               const float* __restrict__ rpwp,
                                               float* __restrict__ dr,
                                               float* __restrict__ dw,
                                               float* __restrict__ nrm) {
  __shared__ float kr[256], kw[256];
  int b = blockIdx.y, tid = threadIdx.x;
  kr[tid] = rpwp[(size_t)b * 1036 + tid];
  kw[tid] = rpwp[(size_t)b * 1036 + 262 + tid];
  __syncthreads();
  int w = tid >> 6, lane = tid & 63;
  float4 kr4 = *(float4*)&kr[lane * 4];
  float4 kw4 = *(float4*)&kw[lane * 4];
  int n0 = blockIdx.x * 16 + w * 4;
  for (int rr = 0; rr < 4; ++rr) {
    int n = n0 + rr;
    const unsigned short* row = mem + ((size_t)b * NN + n) * 256;
    uint2 p = *(const uint2*)(row + lane * 4);
    float m0 = bf2f(p.x & 0xffffu), m1 = bf2f(p.x >> 16);
    float m2 = bf2f(p.y & 0xffffu), m3 = bf2f(p.y >> 16);
    float pr = m0 * kr4.x + m1 * kr4.y + m2 * kr4.z + m3 * kr4.w;
    float pw = m0 * kw4.x + m1 * kw4.y + m2 * kw4.z + m3 * kw4.w;
    float pn = m0 * m0 + m1 * m1 + m2 * m2 + m3 * m3;
#pragma unroll
    for (int o = 32; o > 0; o >>= 1) {
      pr += __shfl_down(pr, o); pw += __shfl_down(pw, o); pn += __shfl_down(pn, o);
    }
    if (lane == 0) {
      dr[(size_t)b * NN + n] = pr;
      dw[(size_t)b * NN + n] = pw;
      nrm[(size_t)b * NN + n] = pn;
    }
  }
}

// ---- addressing ----
__global__ __launch_bounds__(256) void addr_k(const float* __restrict__ dr,
                                              const float* __restrict__ dw,
                                              const float* __restrict__ nrm,
                                              const float* __restrict__ rpwp,
                                              float* rw, float* ww,
                                              float* __restrict__ ea,
                                              float* __restrict__ rvec) {
  __shared__ float wg[4096];
  __shared__ float s8[8];
  int head = blockIdx.x & 1, b = blockIdx.x >> 1;
  int tid = threadIdx.x;
  const float* p = rpwp + (size_t)b * 1036 + (head ? 262 : 0);
  const float* dot = (head ? dw : dr) + (size_t)b * NN;
  const float* n2 = nrm + (size_t)b * NN;
  float* wout = (head ? ww : rw) + (size_t)b * NN;

  float kv = p[tid];
  float kn = sqrtf(blk_sum(kv * kv, s8)) + EPS_;
  float beta = p[256], gate = p[257], sh0 = p[258], sh1 = p[259], sh2 = p[260], gamma = p[261];
  float spb = softplusf_(beta);
  float g = sigf(gate);
  float mx3 = fmaxf(sh0, fmaxf(sh1, sh2));
  float e0 = expf(sh0 - mx3), e1 = expf(sh1 - mx3), e2 = expf(sh2 - mx3);
  float esum = e0 + e1 + e2;
  float s0 = e0 / esum, s1 = e1 / esum, s2 = e2 / esum;
  float gp = 1.f + softplusf_(gamma);

  float l[16];
  float lmax = -1e30f;
#pragma unroll
  for (int i = 0; i < 16; ++i) {
    int n = tid + i * 256;
    float cs = dot[n] / ((sqrtf(n2[n]) + EPS_) * kn);
    l[i] = spb * cs;
    lmax = fmaxf(lmax, l[i]);
  }
  float Mx = blk_max(lmax, s8);
  float es = 0.f;
#pragma unroll
  for (int i = 0; i < 16; ++i) { l[i] = expf(l[i] - Mx); es += l[i]; }
  float SS = blk_sum(es, s8);
  float inv = 1.f / SS;
#pragma unroll
  for (int i = 0; i < 16; ++i) {
    int n = tid + i * 256;
    wg[n] = g * l[i] * inv + (1.f - g) * wout[n];
  }
  __syncthreads();
  float wt[16];
  float wsum = 0.f;
#pragma unroll
  for (int i = 0; i < 16; ++i) {
    int n = tid + i * 256;
    float sh = s0 * wg[(n + 1) & 4095] + s1 * wg[n] + s2 * wg[(n + 4095) & 4095];
    wt[i] = powf(sh + EPS_, gp);
    wsum += wt[i];
  }
  float WS = blk_sum(wsum, s8) + EPS_;
  float winv = 1.f / WS;
#pragma unroll
  for (int i = 0; i < 16; ++i) wout[tid + i * 256] = wt[i] * winv;

  if (head) {
    ea[(size_t)b * 512 + tid] = sigf(p[262 + tid]);
    ea[(size_t)b * 512 + 256 + tid] = tanhf(p[518 + tid]);
  } else {
    rvec[(size_t)b * 256 + tid] = 0.f;
  }
}

// ---- pass B over bf16 memory: erase/add + fused r = rw . mem_new ----
template <int FIRST>
__global__ __launch_bounds__(256) void passB_k(unsigned short* mem, const float* __restrict__ ww,
                                               const float* __restrict__ rw,
                                               const float* __restrict__ ea,
                                               float* __restrict__ rvec) {
  __shared__ float eS[256], aS[256];
  __shared__ float rred[4][256];
  int b = blockIdx.y, tid = threadIdx.x;
  eS[tid] = ea[(size_t)b * 512 + tid];
  aS[tid] = ea[(size_t)b * 512 + 256 + tid];
  __syncthreads();
  int w = tid >> 6, lane = tid & 63;
  float4 e4 = *(float4*)&eS[lane * 4];
  float4 a4 = *(float4*)&aS[lane * 4];
  float4 racc = make_float4(0.f, 0.f, 0.f, 0.f);
  int n0 = blockIdx.x * 128 + w * 32;
  for (int rr = 0; rr < 32; ++rr) {
    int n = n0 + rr;
    float wt = ww[(size_t)b * NN + n];
    float rwv = rw[(size_t)b * NN + n];
    unsigned short* row = mem + ((size_t)b * NN + n) * 256;
    float m0, m1, m2, m3;
    if (FIRST) {
      m0 = wt * a4.x; m1 = wt * a4.y; m2 = wt * a4.z; m3 = wt * a4.w;
    } else {
      uint2 p = *(const uint2*)(row + lane * 4);
      m0 = bf2f(p.x & 0xffffu) * (1.f - wt * e4.x) + wt * a4.x;
      m1 = bf2f(p.x >> 16) * (1.f - wt * e4.y) + wt * a4.y;
      m2 = bf2f(p.y & 0xffffu) * (1.f - wt * e4.z) + wt * a4.z;
      m3 = bf2f(p.y >> 16) * (1.f - wt * e4.w) + wt * a4.w;
    }
    uint2 pk;
    pk.x = f2bf(m0) | (f2bf(m1) << 16);
    pk.y = f2bf(m2) | (f2bf(m3) << 16);
    *(uint2*)(row + lane * 4) = pk;
    racc.x += rwv * m0; racc.y += rwv * m1; racc.z += rwv * m2; racc.w += rwv * m3;
  }
  rred[w][lane * 4 + 0] = racc.x;
  rred[w][lane * 4 + 1] = racc.y;
  rred[w][lane * 4 + 2] = racc.z;
  rred[w][lane * 4 + 3] = racc.w;
  __syncthreads();
  float s = rred[0][tid] + rred[1][tid] + rred[2][tid] + rred[3][tid];
  atomicAdd(rvec + (size_t)b * 256 + tid, s);
}

extern "C" void kernel_launch(void* const* d_in, const int* in_sizes, int n_in,
                              void* d_out, int out_size, void* d_ws, size_t ws_size,
                              hipStream_t stream) {
  const int* tokens = (const int*)d_in[0];
  const float* emb_W = (const float*)d_in[1];
  const float* read_gate_W = (const float*)d_in[2];
  const float* read_gate_b = (const float*)d_in[3];
  const float* film_W = (const float*)d_in[4];
  const float* film_b = (const float*)d_in[5];
  const float* t_Wqkv = (const float*)d_in[6];
  const float* t_bqkv = (const float*)d_in[7];
  const float* t_Wo = (const float*)d_in[8];
  const float* t_bo = (const float*)d_in[9];
  const float* t_ln1_g = (const float*)d_in[10];
  const float* t_ln1_b = (const float*)d_in[11];
  const float* t_ln2_g = (const float*)d_in[12];
  const float* t_ln2_b = (const float*)d_in[13];
  const float* t_W1 = (const float*)d_in[14];
  const float* t_b1 = (const float*)d_in[15];
  const float* t_W2 = (const float*)d_in[16];
  const float* t_b2 = (const float*)d_in[17];
  const float* out_ln_g = (const float*)d_in[18];
  const float* out_ln_b = (const float*)d_in[19];
  const float* lstm_Wih = (const float*)d_in[20];
  const float* lstm_Whh = (const float*)d_in[21];
  const float* lstm_bih = (const float*)d_in[22];
  const float* lstm_bhh = (const float*)d_in[23];
  const float* head_W = (const float*)d_in[24];
  const float* head_b = (const float*)d_in[25];
  const float* read_W = (const float*)d_in[26];
  const float* read_b = (const float*)d_in[27];
  const float* write_W = (const float*)d_in[28];
  const float* write_b = (const float*)d_in[29];
  float* out = (float*)d_out;

  float* ws = (float*)d_ws;
  size_t off = 0;
  // ---- zero-initialized region ----
  float* read_w = ws + off; off += (size_t)BB * NN;
  float* write_w = ws + off; off += (size_t)BB * NN;
  float* cx = ws + off; off += 2 * BB * DD;
  float* r_vec = ws + off; off += BB * DD;
  float* dot_r = ws + off; off += (size_t)BB * NN;
  float* dot_w = ws + off; off += (size_t)BB * NN;
  float* norm2 = ws + off; off += (size_t)BB * NN;
  unsigned short* record_b = (unsigned short*)(ws + off); off += BB * DD / 2;
  unsigned short* lstm_in_b = (unsigned short*)(ws + off); off += 2 * BB * 512 / 2;
  size_t zero_floats = off;
  // ---- not zeroed ----
  unsigned short* memory = (unsigned short*)(ws + off); off += (size_t)BB * NN * DD / 2;
  float* hpe = ws + off; off += 9 * BB * DD;
  float* h = ws + off; off += 9 * BB * DD;
  float* h2 = ws + off; off += BB * DD;
  float* qkvC = ws + off; off += 9 * BB * 768;
  float* qkv2 = ws + off; off += 9 * BB * 768;
  float* fp = ws + off; off += BB * 768;
  float* c_out = ws + off; off += BB * DD;
  float* rpwp = ws + off; off += BB * 1036;
  float* ea = ws + off; off += BB * 2 * DD;
  unsigned short* q1b = (unsigned short*)(ws + off); off += 9 * BB * DD / 2;
  unsigned short* q2b = (unsigned short*)(ws + off); off += 9 * BB * DD / 2;
  unsigned short* x2b = (unsigned short*)(ws + off); off += 9 * BB * DD / 2;
  unsigned short* x2b2 = (unsigned short*)(ws + off); off += BB * DD / 2;
  unsigned short* ao_b = (unsigned short*)(ws + off); off += 9 * BB * DD / 2;
  unsigned short* ao2_b = (unsigned short*)(ws + off); off += BB * DD / 2;
  unsigned short* mid_b = (unsigned short*)(ws + off); off += 9 * BB * 1024 / 2;
  unsigned short* cfinb = (unsigned short*)(ws + off); off += BB * DD / 2;
  unsigned short* Wh = (unsigned short*)(ws + off); off += (size_t)VV * 256 / 2;
  unsigned short* Wq_b = (unsigned short*)(ws + off); off += 2 * 768 * 256 / 2;
  unsigned short* Wo_b = (unsigned short*)(ws + off); off += 2 * 256 * 256 / 2;
  unsigned short* W1_b = (unsigned short*)(ws + off); off += 2 * 1024 * 256 / 2;
  unsigned short* W2_b = (unsigned short*)(ws + off); off += 2 * 256 * 1024 / 2;
  unsigned short* Wc_b = (unsigned short*)(ws + off); off += 2 * 1024 * 512 / 2;
  unsigned short* Wrw_b = (unsigned short*)(ws + off); off += 1088 * 256 / 2;
  unsigned short* FR_b = (unsigned short*)(ws + off); off += 768 * 256 / 2;
  float* cb2 = ws + off; off += 2 * 1024;
  float* brw = ws + off; off += 1040;
  float* brc = ws + off; off += 768;
  if (ws_size < off * sizeof(float)) return;

  (void)hipMemsetAsync(ws, 0, zero_floats * sizeof(float), stream);
  (void)hipMemsetAsync(Wrw_b + (size_t)1036 * 256, 0, (size_t)52 * 256 * 2, stream);
  init_k<<<32, 256, 0, stream>>>(read_w, write_w, hpe);
  cvtw_k<<<(VV * 256 / 4 + 255) / 256, 256, 0, stream>>>(head_W, Wh, VV * 256 / 4);
  cvtw_k<<<(2 * 768 * 256 / 4 + 255) / 256, 256, 0, stream>>>(t_Wqkv, Wq_b, 2 * 768 * 256 / 4);
  cvtw_k<<<(2 * 256 * 256 / 4 + 255) / 256, 256, 0, stream>>>(t_Wo, Wo_b, 2 * 256 * 256 / 4);
  cvtw_k<<<(2 * 1024 * 256 / 4 + 255) / 256, 256, 0, stream>>>(t_W1, W1_b, 2 * 1024 * 256 / 4);
  cvtw_k<<<(2 * 256 * 1024 / 4 + 255) / 256, 256, 0, stream>>>(t_W2, W2_b, 2 * 256 * 1024 / 4);
  cvtw_k<<<(512 * 256 / 4 + 255) / 256, 256, 0, stream>>>(film_W, FR_b, 512 * 256 / 4);
  cvtw_k<<<(256 * 256 / 4 + 255) / 256, 256, 0, stream>>>(read_gate_W, FR_b + 512 * 256, 256 * 256 / 4);
  catlstm_k<<<4096, 256, 0, stream>>>(lstm_Wih, lstm_Whh, lstm_bih, lstm_bhh, Wc_b, cb2);
  catrw_k<<<1036, 256, 0, stream>>>(read_W, read_b, write_W, write_b, Wrw_b, brw);
  brc_k<<<3, 256, 0, stream>>>(film_b, read_gate_b, brc);
  ln0_k<<<BB, 256, 0, stream>>>(hpe, t_ln1_g, t_ln1_b, q1b);
  gA_k<0><<<dim3(12, 1), 256, 0, stream>>>(q1b, Wq_b, t_bqkv, qkvC, nullptr, 768, 768);

  for (int t = 0; t < TT; ++t) {
    const int S = t + 2;

    // x_in: FiLM/gate GEMM + pointwise (writes hpe row t+1, q1b row t+1)
    gA_k<0><<<dim3(12, 1), 256, 0, stream>>>(record_b, FR_b, brc, fp, nullptr, 768, 768);
    xinpw_k<<<BB, 256, 0, stream>>>(tokens, emb_W, fp, r_vec, t_ln1_g, t_ln1_b, hpe, q1b, t);
    // layer-1 qkv: only the new row (old rows cached)
    gA_k<0><<<dim3(12, 1), 256, 0, stream>>>(q1b + (size_t)(t + 1) * BB * 256, Wq_b, t_bqkv,
                                             qkvC + (size_t)(t + 1) * BB * 768, nullptr, 768, 768);
    attn_k<<<BB * 4, 128, 0, stream>>>(qkvC, ao_b, S);
    gB_k<256, 0><<<S, 256, 0, stream>>>(ao_b, Wo_b, t_bo, hpe, h, t_ln2_g, t_ln2_b, x2b, 256, nullptr);
    gA_k<1><<<dim3(16, S), 256, 0, stream>>>(x2b, W1_b, t_b1, nullptr, mid_b, 1024, 1024);
    gB_k<1024, 0><<<S, 256, 0, stream>>>(mid_b, W2_b, t_b2, h, h, t_ln1_g + 256, t_ln1_b + 256, q2b, 256, nullptr);

    // layer-2
    gA_k<0><<<dim3(12, S), 256, 0, stream>>>(q2b, Wq_b + 768 * 256, t_bqkv + 768, qkv2, nullptr, 768, 768);
    attnl_k<<<BB * 4, 64, 0, stream>>>(qkv2, ao2_b, S);
    gB_k<256, 0><<<1, 256, 0, stream>>>(ao2_b, Wo_b + 256 * 256, t_bo + 256, h + (size_t)(S - 1) * BB * 256,
                                        h2, t_ln2_g + 256, t_ln2_b + 256, x2b2, 256, nullptr);
    gA_k<1><<<dim3(16, 1), 256, 0, stream>>>(x2b2, W1_b + 1024 * 256, t_b1 + 1024, nullptr, mid_b, 1024, 1024);
    gB_k<1024, 1><<<1, 256, 0, stream>>>(mid_b, W2_b + 256 * 1024, t_b2 + 256, h2, h2,
                                         out_ln_g, out_ln_b, lstm_in_b, 512, c_out);

    // LSTM
    gL_k<0><<<16, 256, 0, stream>>>(lstm_in_b, Wc_b, cb2, cx, lstm_in_b, lstm_in_b + BB * 512,
                                    nullptr, nullptr, nullptr);
    gL_k<1><<<16, 256, 0, stream>>>(lstm_in_b + BB * 512, Wc_b + (size_t)1024 * 512, cb2 + 1024,
                                    cx + BB * DD, lstm_in_b + BB * 512, nullptr, c_out, cfinb, record_b);

    head_k<<<(VV + 63) / 64, 256, 0, stream>>>(Wh, cfinb, head_b, out + (size_t)t * BB * VV);

    if (t < TT - 1) {
      gA_k<0><<<dim3(17, 1), 256, 0, stream>>>(cfinb, Wrw_b, brw, rpwp, nullptr, 1036, 1036);
      if (t > 0)
        passA_k<<<dim3(NN / 16, BB), 256, 0, stream>>>(memory, rpwp, dot_r, dot_w, norm2);
      addr_k<<<2 * BB, 256, 0, stream>>>(dot_r, dot_w, norm2, rpwp, read_w, write_w, ea, r_vec);
      if (t == 0)
        passB_k<1><<<dim3(NN / 128, BB), 256, 0, stream>>>(memory, write_w, read_w, ea, r_vec);
      else
        passB_k<0><<<dim3(NN / 128, BB), 256, 0, stream>>>(memory, write_w, read_w, ea, r_vec);
    }
  }
}